// Round 1
// baseline (335.361 us; speedup 1.0000x reference)
//
#include <hip/hip_runtime.h>
#include <math.h>

#define IN_DIM 256
#define OUT_DIM 128
#define NH 8
#define HD 16
#define GH 16
#define TBL 1024
#define LOG2E 1.44269504f
// R12: atomic counters padded to one per 128B cache line (32 ints).
// deg lives at degpad[i*32], cursor at degpad[i*32+16] (same line, but their
// atomic phases don't overlap: deg atomics end before scan; cursor atomics
// start after). Theory: 800k atomics on 50000 COMPACT ints = ~1563 lines,
// ~6-7 concurrent RMWs per line always colliding -> same-line serialization
// = the ~55us idle tail that pins qkv_deg at 82.6us (MfmaUtil 7.5% despite
// GEMM work being only ~25-35us). Padding makes nearly all in-flight atomics
// hit distinct lines -> pipelined at L2 rate.
#define DPAD 32

typedef __attribute__((ext_vector_type(8))) short short8;
typedef __attribute__((ext_vector_type(4))) float floatx4;

// ---------------- bf16 helpers (RNE) ----------------
__device__ __forceinline__ unsigned short f2bf(float f) {
    union { float f; unsigned u; } v; v.f = f;
    unsigned r = v.u + 0x7fffu + ((v.u >> 16) & 1u);
    return (unsigned short)(r >> 16);
}
__device__ __forceinline__ float bf2f(unsigned short h) {
    union { unsigned u; float f; } v; v.u = ((unsigned)h) << 16;
    return v.f;
}
__device__ __forceinline__ void split1(float f, unsigned short& h, unsigned short& l) {
    h = f2bf(f);
    l = f2bf(f - bf2f(h));
}
__device__ __forceinline__ float bflo(unsigned u) { return __uint_as_float(u << 16); }
__device__ __forceinline__ float bfhi(unsigned u) { return __uint_as_float(u & 0xffff0000u); }

// ---------------- prep_all: split x, split Wq/Wk/Wv/Wo, geo table, zero degpad+part ----------------
__global__ __launch_bounds__(256) void prep_all_kernel(
    const float* __restrict__ x, const float* __restrict__ Wq, const float* __restrict__ Wk,
    const float* __restrict__ Wv, const float* __restrict__ Wo,
    unsigned short* __restrict__ xh, unsigned short* __restrict__ xl,
    unsigned short* __restrict__ wh, unsigned short* __restrict__ wl,
    unsigned short* __restrict__ wo_h, unsigned short* __restrict__ wo_l,
    const float* __restrict__ Wg1, const float* __restrict__ bg1,
    const float* __restrict__ Wg2, const float* __restrict__ bg2,
    float* __restrict__ tbl, int* __restrict__ deg, int* __restrict__ part,
    int n4x, int Nzero, int nsplit, int nwm, int nwo, int ngeo, int ndegz) {
    int bx = blockIdx.x;
    int t = threadIdx.x;

    if (bx < nsplit) {                       // split x
        int i = bx * 256 + t;
        if (i >= n4x) return;
        float4 f = ((const float4*)x)[i];
        ushort4 h, l;
        split1(f.x, h.x, l.x); split1(f.y, h.y, l.y);
        split1(f.z, h.z, l.z); split1(f.w, h.w, l.w);
        ((ushort4*)xh)[i] = h;
        ((ushort4*)xl)[i] = l;
        return;
    }
    bx -= nsplit;
    if (bx < 3 * nwm) {                      // split Wq/Wk/Wv
        int m = bx / nwm;
        int i = (bx - m * nwm) * 256 + t;
        if (i >= (OUT_DIM * IN_DIM) / 4) return;
        const float* W = (m == 0) ? Wq : (m == 1) ? Wk : Wv;
        float4 f = ((const float4*)W)[i];
        ushort4 h, l;
        split1(f.x, h.x, l.x); split1(f.y, h.y, l.y);
        split1(f.z, h.z, l.z); split1(f.w, h.w, l.w);
        size_t base = (size_t)m * (OUT_DIM * IN_DIM) / 4;
        ((ushort4*)wh)[base + i] = h;
        ((ushort4*)wl)[base + i] = l;
        return;
    }
    bx -= 3 * nwm;
    if (bx < nwo) {                          // split Wo
        int i = bx * 256 + t;
        if (i >= (OUT_DIM * OUT_DIM) / 4) return;
        float4 f = ((const float4*)Wo)[i];
        ushort4 h, l;
        split1(f.x, h.x, l.x); split1(f.y, h.y, l.y);
        split1(f.z, h.z, l.z); split1(f.w, h.w, l.w);
        ((ushort4*)wo_h)[i] = h;
        ((ushort4*)wo_l)[i] = l;
        return;
    }
    bx -= nwo;
    if (bx < ngeo) {                         // geo bias table (log2-domain)
        int i = bx * 256 + t;
        if (i >= TBL) return;
        float d = (float)i * (6.0f / (float)(TBL - 1));
        float rbf[GH];
#pragma unroll
        for (int j = 0; j < GH; ++j) {
            float c = 0.4f * (float)j;
            float tt = d - c;
            rbf[j] = __expf(-tt * tt);
        }
        float hid[GH];
#pragma unroll
        for (int j = 0; j < GH; ++j) {
            float acc = bg1[j];
#pragma unroll
            for (int kk = 0; kk < GH; ++kk) acc += rbf[kk] * Wg1[j * GH + kk];
            hid[j] = fmaxf(acc, 0.0f);
        }
#pragma unroll
        for (int h = 0; h < NH; ++h) {
            float acc = bg2[h];
#pragma unroll
            for (int j = 0; j < GH; ++j) acc += hid[j] * Wg2[h * GH + j];
            tbl[i * NH + h] = acc * LOG2E;
        }
        return;
    }
    bx -= ngeo;
    if (bx < ndegz) {                        // zero degpad (int4, full 6.4MB)
        int idx4 = (bx * 256 + t) * 4;
        if (idx4 + 3 < Nzero) {
            *(int4*)(deg + idx4) = make_int4(0, 0, 0, 0);
        } else {
#pragma unroll
            for (int j = 0; j < 4; ++j) if (idx4 + j < Nzero) deg[idx4 + j] = 0;
        }
        return;
    }
    if (t < 256) part[t] = 0;
}

// ---------------- qkv (128x128 tile) + deg count, one dispatch ----------------
// R11 post-mortem: 64x128 tile, 3 error-correction passes everywhere = 343 TF plateau
// (MfmaUtil 13.5%). q/k feed ONLY logits -> 1-pass pure-bf16 is accuracy-safe
// (dlogit ~2e-3); v keeps 3-pass split (its error hits the output linearly).
// 128-row tile doubles MFMA per barrier and halves x re-staging.
__global__ __launch_bounds__(256) void qkv_deg_kernel(
    const unsigned short* __restrict__ xh, const unsigned short* __restrict__ xl,
    const unsigned short* __restrict__ wh, const unsigned short* __restrict__ wl,
    const float* __restrict__ bq, const float* __restrict__ bk, const float* __restrict__ bv,
    float* __restrict__ q, unsigned short* __restrict__ kb, unsigned short* __restrict__ vb,
    const int* __restrict__ ei, int* __restrict__ deg, int Nn, int E_, int nxb) {
    int bx = blockIdx.x;
    if (bx >= 3 * nxb) {                     // deg blocks (padded counters)
        int e = (bx - 3 * nxb) * 256 + threadIdx.x;
        if (e < E_) atomicAdd(&deg[ei[e] * DPAD], 1);
        return;
    }
    const int wsel = bx / nxb;
    const int n0 = (bx - wsel * nxb) * 128;
    const unsigned short* W_h = wh + (size_t)wsel * (OUT_DIM * IN_DIM);
    const unsigned short* W_l = wl + (size_t)wsel * (OUT_DIM * IN_DIM);
    const float* bias = (wsel == 0) ? bq : (wsel == 1) ? bk : bv;
    const bool vpath = (wsel == 2);

    __shared__ unsigned short xh_s[128 * 40];
    __shared__ unsigned short xl_s[128 * 40];
    __shared__ unsigned short wh_s[128 * 40];
    __shared__ unsigned short wl_s[128 * 40];

    const int tid = threadIdx.x;
    const int w = tid >> 6;
    const int lane = tid & 63;
    const int ml = lane & 15;
    const int quad = lane >> 4;

    const int rows_valid = min(128, Nn - n0);

    floatx4 acc[2][8];
#pragma unroll
    for (int rr = 0; rr < 2; ++rr)
#pragma unroll
        for (int ct = 0; ct < 8; ++ct) acc[rr][ct] = (floatx4){0.f, 0.f, 0.f, 0.f};

    const short8 zero8 = {0, 0, 0, 0, 0, 0, 0, 0};

    for (int kc = 0; kc < IN_DIM; kc += 32) {
#pragma unroll
        for (int l = 0; l < 2; ++l) {
            int flat = tid + l * 256;        // 0..511 -> r 0..127, c 0..3 (8-short chunks)
            int r = flat >> 2, c = flat & 3;
            size_t gx = (size_t)(n0 + r) * IN_DIM + kc + c * 8;
            size_t gw = (size_t)r * IN_DIM + kc + c * 8;
            short8 vh = zero8;
            if (r < rows_valid) vh = *(const short8*)(xh + gx);
            *(short8*)(xh_s + r * 40 + c * 8) = vh;
            *(short8*)(wh_s + r * 40 + c * 8) = *(const short8*)(W_h + gw);
            if (vpath) {
                short8 vl = zero8;
                if (r < rows_valid) vl = *(const short8*)(xl + gx);
                *(short8*)(xl_s + r * 40 + c * 8) = vl;
                *(short8*)(wl_s + r * 40 + c * 8) = *(const short8*)(W_l + gw);
            }
        }
        __syncthreads();

        short8 ah0 = *(const short8*)(xh_s + (w * 32 + ml) * 40 + quad * 8);
        short8 ah1 = *(const short8*)(xh_s + (w * 32 + 16 + ml) * 40 + quad * 8);
        if (!vpath) {
#pragma unroll
            for (int ct = 0; ct < 8; ++ct) {
                short8 bh = *(const short8*)(wh_s + (ct * 16 + ml) * 40 + quad * 8);
                acc[0][ct] = __builtin_amdgcn_mfma_f32_16x16x32_bf16(ah0, bh, acc[0][ct], 0, 0, 0);
                acc[1][ct] = __builtin_amdgcn_mfma_f32_16x16x32_bf16(ah1, bh, acc[1][ct], 0, 0, 0);
            }
        } else {
            short8 al0 = *(const short8*)(xl_s + (w * 32 + ml) * 40 + quad * 8);
            short8 al1 = *(const short8*)(xl_s + (w * 32 + 16 + ml) * 40 + quad * 8);
#pragma unroll
            for (int ct = 0; ct < 8; ++ct) {
                short8 bh = *(const short8*)(wh_s + (ct * 16 + ml) * 40 + quad * 8);
                short8 bl = *(const short8*)(wl_s + (ct * 16 + ml) * 40 + quad * 8);
                acc[0][ct] = __builtin_amdgcn_mfma_f32_16x16x32_bf16(ah0, bh, acc[0][ct], 0, 0, 0);
                acc[0][ct] = __builtin_amdgcn_mfma_f32_16x16x32_bf16(al0, bh, acc[0][ct], 0, 0, 0);
                acc[0][ct] = __builtin_amdgcn_mfma_f32_16x16x32_bf16(ah0, bl, acc[0][ct], 0, 0, 0);
                acc[1][ct] = __builtin_amdgcn_mfma_f32_16x16x32_bf16(ah1, bh, acc[1][ct], 0, 0, 0);
                acc[1][ct] = __builtin_amdgcn_mfma_f32_16x16x32_bf16(al1, bh, acc[1][ct], 0, 0, 0);
                acc[1][ct] = __builtin_amdgcn_mfma_f32_16x16x32_bf16(ah1, bl, acc[1][ct], 0, 0, 0);
            }
        }
        __syncthreads();
    }

    if (wsel == 0) {
#pragma unroll
        for (int rr = 0; rr < 2; ++rr)
#pragma unroll
            for (int ct = 0; ct < 8; ++ct) {
                float bj = bias[ct * 16 + ml];
#pragma unroll
                for (int r = 0; r < 4; ++r) {
                    int grow = n0 + w * 32 + rr * 16 + quad * 4 + r;
                    if (grow < Nn) q[(size_t)grow * 128 + ct * 16 + ml] = acc[rr][ct][r] + bj;
                }
            }
    } else {
        unsigned short* ob = (wsel == 1) ? kb : vb;
#pragma unroll
        for (int rr = 0; rr < 2; ++rr)
#pragma unroll
            for (int ct = 0; ct < 8; ++ct) {
                float bj = bias[ct * 16 + ml];
#pragma unroll
                for (int r = 0; r < 4; ++r) {
                    int grow = n0 + w * 32 + rr * 16 + quad * 4 + r;
                    if (grow < Nn) ob[(size_t)grow * 128 + ct * 16 + ml] = f2bf(acc[rr][ct][r] + bj);
                }
            }
    }
}

// ---------------- one-dispatch exclusive scan (decoupled lookback, nblk<=256 blocks) ----------------
// R12: deg read strided (deg[i*DPAD]); cursor written strided (cursor[i*DPAD]).
__global__ __launch_bounds__(256) void scan_onepass_kernel(
    const int* __restrict__ deg, int* __restrict__ part,
    int* __restrict__ rowstart, int* __restrict__ cursor, int n, int nblk) {
    __shared__ int sm[256];
    int b = blockIdx.x;
    int t = threadIdx.x;
    int idx4 = b * 1024 + t * 4;
    int d0 = 0, d1 = 0, d2 = 0, d3 = 0;
    if (idx4 + 0 < n) d0 = deg[(size_t)(idx4 + 0) * DPAD];
    if (idx4 + 1 < n) d1 = deg[(size_t)(idx4 + 1) * DPAD];
    if (idx4 + 2 < n) d2 = deg[(size_t)(idx4 + 2) * DPAD];
    if (idx4 + 3 < n) d3 = deg[(size_t)(idx4 + 3) * DPAD];
    int s = d0 + d1 + d2 + d3;
    sm[t] = s;
    __syncthreads();
    for (int off = 1; off < 256; off <<= 1) {
        int o = (t >= off) ? sm[t - off] : 0;
        __syncthreads();
        sm[t] += o;
        __syncthreads();
    }
    int myprefix = sm[t] - s;
    int total = sm[255];
    __syncthreads();

    if (t == 0) atomicExch(&part[b], total + 1);

    int pv = 0;
    if (t < b) {
        while ((pv = atomicAdd(&part[t], 0)) == 0) {}
        pv -= 1;
    }
    sm[t] = (t < b) ? pv : 0;
    __syncthreads();
    for (int off = 128; off > 0; off >>= 1) {
        if (t < off) sm[t] += sm[t + off];
        __syncthreads();
    }
    int offset = sm[0];

    int run = offset + myprefix;
    int rv[4];
    rv[0] = run;
    rv[1] = run + d0;
    rv[2] = rv[1] + d1;
    rv[3] = rv[2] + d2;
    if (idx4 + 3 < n) {
        *(int4*)(rowstart + idx4) = make_int4(rv[0], rv[1], rv[2], rv[3]);
    } else {
#pragma unroll
        for (int j = 0; j < 4; ++j)
            if (idx4 + j < n) rowstart[idx4 + j] = rv[j];
    }
#pragma unroll
    for (int j = 0; j < 4; ++j)
        if (idx4 + j < n) cursor[(size_t)(idx4 + j) * DPAD] = rv[j];
    if (b == nblk - 1 && t == 255) rowstart[n] = offset + total;
}

// ---------------- scatter: {col, table-coord u} packed int2 into CSR order ----------------
// R12: cursor padded (cursor[row*DPAD]) to kill same-line atomic serialization.
__global__ void scatter_kernel(const int* __restrict__ ei, const float* __restrict__ edist,
                               int* __restrict__ cursor, int2* __restrict__ cpack, int E_) {
    int e = blockIdx.x * 256 + threadIdx.x;
    if (e >= E_) return;
    int row = ei[e];
    int pos = atomicAdd(&cursor[row * DPAD], 1);
    float u = edist[e] * ((float)(TBL - 1) / 6.0f);
    u = fminf(fmaxf(u, 0.0f), (float)(TBL - 1));
    cpack[pos] = make_int2(ei[E_ + e], __float_as_int(u));
}

// ---------------- fused flash-style edge+node pass (unchanged from R10) ----------------
__global__ __launch_bounds__(256) void fused_node_kernel(
    const float* __restrict__ q, const unsigned short* __restrict__ kb,
    const unsigned short* __restrict__ vb, const int2* __restrict__ cpack,
    const float* __restrict__ tbl, const int* __restrict__ rowstart,
    unsigned short* __restrict__ oh, unsigned short* __restrict__ ol, int Nn) {
    int lane = threadIdx.x & 63;
    int n = blockIdx.x * 4 + (threadIdx.x >> 6);
    if (n >= Nn) return;
    int g = lane >> 3;       // edge subgroup
    int h = lane & 7;        // head
    int start = rowstart[n];
    int end = rowstart[n + 1];

    float qf[16];
    {
        const float4* qp = (const float4*)(q + (size_t)n * 128 + h * 16);
#pragma unroll
        for (int j = 0; j < 4; ++j) {
            float4 t = qp[j];
            qf[j * 4 + 0] = t.x; qf[j * 4 + 1] = t.y;
            qf[j * 4 + 2] = t.z; qf[j * 4 + 3] = t.w;
        }
    }

    float l = 0.0f;
    float acc[16];
#pragma unroll
    for (int j = 0; j < 16; ++j) acc[j] = 0.0f;

#pragma unroll 2
    for (int base = start; base < end; base += 8) {
        int e = base + g;
        bool valid = (e < end);
        int ee = valid ? e : (end - 1);
        int2 np = cpack[ee];
        int col = np.x;
        float u = __int_as_float(np.y);

        const uint4* kp = (const uint4*)(kb + (size_t)col * 128 + h * 16);
        uint4 k0 = kp[0], k1 = kp[1];
        const uint4* vp = (const uint4*)(vb + (size_t)col * 128 + h * 16);
        uint4 v0 = vp[0], v1 = vp[1];

        unsigned kk[8] = {k0.x, k0.y, k0.z, k0.w, k1.x, k1.y, k1.z, k1.w};
        float d = 0.0f;
#pragma unroll
        for (int j = 0; j < 8; ++j) {
            d = fmaf(bflo(kk[j]), qf[2 * j], d);
            d = fmaf(bfhi(kk[j]), qf[2 * j + 1], d);
        }

        int i0 = min((int)u, TBL - 2);
        float fr = u - (float)i0;
        float t0 = tbl[i0 * NH + h];
        float t1 = tbl[i0 * NH + NH + h];
        float logit2 = fmaf(d, 0.25f * LOG2E, fmaf(fr, t1 - t0, t0));
        logit2 = fminf(logit2, 80.0f);
        if (!valid) logit2 = -1e30f;
        float p = __builtin_amdgcn_exp2f(logit2);

        l += p;
        unsigned vv[8] = {v0.x, v0.y, v0.z, v0.w, v1.x, v1.y, v1.z, v1.w};
#pragma unroll
        for (int j = 0; j < 8; ++j) {
            acc[2 * j]     = fmaf(p, bflo(vv[j]), acc[2 * j]);
            acc[2 * j + 1] = fmaf(p, bfhi(vv[j]), acc[2 * j + 1]);
        }
    }

#pragma unroll
    for (int off = 8; off < 64; off <<= 1) {
        l += __shfl_xor(l, off);
#pragma unroll
        for (int j = 0; j < 16; ++j) acc[j] += __shfl_xor(acc[j], off);
    }

    if (g == 0) {
        float inv = 1.0f / (l + 1e-12f);
        unsigned short hv[16], lv[16];
#pragma unroll
        for (int j = 0; j < 16; ++j) {
            float o = acc[j] * inv;
            split1(o, hv[j], lv[j]);
        }
        *(short8*)(oh + (size_t)n * 128 + h * 16) = *(short8*)hv;
        *(short8*)(oh + (size_t)n * 128 + h * 16 + 8) = *(short8*)(hv + 8);
        *(short8*)(ol + (size_t)n * 128 + h * 16) = *(short8*)lv;
        *(short8*)(ol + (size_t)n * 128 + h * 16 + 8) = *(short8*)(lv + 8);
    }
}

// ---------------- out GEMM via split-bf16 MFMA (K=128) ----------------
__global__ __launch_bounds__(256) void out_gemm_mfma_kernel(
    const unsigned short* __restrict__ oh, const unsigned short* __restrict__ ol,
    const unsigned short* __restrict__ wo_h, const unsigned short* __restrict__ wo_l,
    const float* __restrict__ bo, float* __restrict__ out, int Nn) {
    const int n0 = blockIdx.x * 64;

    __shared__ unsigned short xh_s[64 * 40];
    __shared__ unsigned short xl_s[64 * 40];
    __shared__ unsigned short wh_s[128 * 40];
    __shared__ unsigned short wl_s[128 * 40];

    const int tid = threadIdx.x;
    const int w = tid >> 6;
    const int lane = tid & 63;
    const int ml = lane & 15;
    const int quad = lane >> 4;

    const int rows_valid = min(64, Nn - n0);

    floatx4 acc[8];
#pragma unroll
    for (int ct = 0; ct < 8; ++ct) acc[ct] = (floatx4){0.f, 0.f, 0.f, 0.f};

    const short8 zero8 = {0, 0, 0, 0, 0, 0, 0, 0};

    for (int kc = 0; kc < OUT_DIM; kc += 32) {
        {
            int r = tid >> 2, c = tid & 3;
            short8 vh = zero8, vl = zero8;
            if (r < rows_valid) {
                size_t g = (size_t)(n0 + r) * OUT_DIM + kc + c * 8;
                vh = *(const short8*)(oh + g);
                vl = *(const short8*)(ol + g);
            }
            *(short8*)(xh_s + r * 40 + c * 8) = vh;
            *(short8*)(xl_s + r * 40 + c * 8) = vl;
        }
#pragma unroll
        for (int l = 0; l < 2; ++l) {
            int idx = tid + l * 256;
            int r = idx >> 2, c = idx & 3;
            size_t g = (size_t)r * OUT_DIM + kc + c * 8;
            *(short8*)(wh_s + r * 40 + c * 8) = *(const short8*)(wo_h + g);
            *(short8*)(wl_s + r * 40 + c * 8) = *(const short8*)(wo_l + g);
        }
        __syncthreads();

        short8 ah = *(const short8*)(xh_s + (w * 16 + ml) * 40 + quad * 8);
        short8 al = *(const short8*)(xl_s + (w * 16 + ml) * 40 + quad * 8);
#pragma unroll
        for (int ct = 0; ct < 8; ++ct) {
            short8 bh = *(const short8*)(wh_s + (ct * 16 + ml) * 40 + quad * 8);
            short8 bl = *(const short8*)(wl_s + (ct * 16 + ml) * 40 + quad * 8);
            acc[ct] = __builtin_amdgcn_mfma_f32_16x16x32_bf16(ah, bh, acc[ct], 0, 0, 0);
            acc[ct] = __builtin_amdgcn_mfma_f32_16x16x32_bf16(al, bh, acc[ct], 0, 0, 0);
            acc[ct] = __builtin_amdgcn_mfma_f32_16x16x32_bf16(ah, bl, acc[ct], 0, 0, 0);
        }
        __syncthreads();
    }

#pragma unroll
    for (int ct = 0; ct < 8; ++ct) {
        float bj = bo[ct * 16 + ml];
#pragma unroll
        for (int r = 0; r < 4; ++r) {
            int grow = n0 + w * 16 + quad * 4 + r;
            if (grow < Nn) out[(size_t)grow * 128 + ct * 16 + ml] = acc[ct][r] + bj;
        }
    }
}

extern "C" void kernel_launch(void* const* d_in, const int* in_sizes, int n_in,
                              void* d_out, int out_size, void* d_ws, size_t ws_size,
                              hipStream_t stream) {
    const float* x   = (const float*)d_in[0];
    const int* ei    = (const int*)d_in[1];
    const float* edist = (const float*)d_in[2];
    const float* Wq = (const float*)d_in[3];  const float* bq = (const float*)d_in[4];
    const float* Wk = (const float*)d_in[5];  const float* bk = (const float*)d_in[6];
    const float* Wv = (const float*)d_in[7];  const float* bv = (const float*)d_in[8];
    const float* Wo = (const float*)d_in[9];  const float* bo = (const float*)d_in[10];
    const float* Wg1 = (const float*)d_in[11]; const float* bg1 = (const float*)d_in[12];
    const float* Wg2 = (const float*)d_in[13]; const float* bg2 = (const float*)d_in[14];
    const int Nn = in_sizes[0] / IN_DIM;
    const int Ee = in_sizes[2];
    float* out = (float*)d_out;

    char* ws = (char*)d_ws;
    size_t off = 0;
    auto alloc = [&](size_t bytes) -> char* {
        char* p = ws + off;
        off += (bytes + 255) & ~(size_t)255;
        return p;
    };
    float* q  = (float*)alloc((size_t)Nn * 128 * 4);
    unsigned short* kbuf = (unsigned short*)alloc((size_t)Nn * 128 * 2);
    unsigned short* vbuf = (unsigned short*)alloc((size_t)Nn * 128 * 2);
    char* xlblock = alloc((size_t)Nn * IN_DIM * 2);
    unsigned short* o_hi = (unsigned short*)alloc((size_t)Nn * 128 * 2);
    unsigned short* o_lo = (unsigned short*)alloc((size_t)Nn * 128 * 2);
    float* geot = (float*)alloc((size_t)TBL * 8 * 4);
    int* degpad   = (int*)alloc((size_t)Nn * DPAD * 4);   // R12: padded counters (deg @ +0, cursor @ +16)
    int* rowstart = (int*)alloc((size_t)(Nn + 1) * 4);
    int* part     = (int*)alloc((size_t)256 * 4);
    unsigned short* wh_all = (unsigned short*)alloc((size_t)3 * OUT_DIM * IN_DIM * 2);
    unsigned short* wl_all = (unsigned short*)alloc((size_t)3 * OUT_DIM * IN_DIM * 2);
    unsigned short* wo_h = (unsigned short*)alloc((size_t)OUT_DIM * OUT_DIM * 2);
    unsigned short* wo_l = (unsigned short*)alloc((size_t)OUT_DIM * OUT_DIM * 2);

    int* deg    = degpad;          // deg[i*DPAD]
    int* cursor = degpad + 16;     // cursor[i*DPAD] (same line as deg[i], disjoint lifetime)

    unsigned short* xh = (unsigned short*)d_out;       // rewritten by final GEMM
    unsigned short* xl = (unsigned short*)xlblock;
    int2* cpack = (int2*)xlblock;                       // live after qkv

    // --- dispatch 1: prep_all ---
    int n4x = Nn * IN_DIM / 4;
    int nsplit = (n4x + 255) / 256;
    int nwm = ((OUT_DIM * IN_DIM / 4) + 255) / 256;
    int nwo = ((OUT_DIM * OUT_DIM / 4) + 255) / 256;
    int ngeo = (TBL + 255) / 256;
    int Nzero = Nn * DPAD;
    int ndegz = (Nzero + 1023) / 1024;
    int gprep = nsplit + 3 * nwm + nwo + ngeo + ndegz + 1;
    prep_all_kernel<<<gprep, 256, 0, stream>>>(
        x, Wq, Wk, Wv, Wo, xh, xl, wh_all, wl_all, wo_h, wo_l,
        Wg1, bg1, Wg2, bg2, geot, deg, part, n4x, Nzero, nsplit, nwm, nwo, ngeo, ndegz);

    // --- dispatch 2: qkv (128-row tiles) + deg ---
    int nxb = (Nn + 127) / 128;
    int ndegb = (Ee + 255) / 256;
    qkv_deg_kernel<<<3 * nxb + ndegb, 256, 0, stream>>>(
        xh, xl, wh_all, wl_all, bq, bk, bv, q, kbuf, vbuf, ei, deg, Nn, Ee, nxb);

    // --- dispatch 3: one-pass scan ---
    int nblk = (Nn + 1023) / 1024;
    scan_onepass_kernel<<<nblk, 256, 0, stream>>>(deg, part, rowstart, cursor, Nn, nblk);

    // --- dispatch 4: scatter ---
    scatter_kernel<<<(Ee + 255) / 256, 256, 0, stream>>>(ei, edist, cursor, cpack, Ee);

    // --- dispatch 5: fused edge+node ---
    fused_node_kernel<<<(Nn + 3) / 4, 256, 0, stream>>>(q, kbuf, vbuf, cpack, geot, rowstart, o_hi, o_lo, Nn);

    // --- dispatch 6: out GEMM ---
    out_gemm_mfma_kernel<<<(Nn + 63) / 64, 256, 0, stream>>>(o_hi, o_lo, wo_h, wo_l, bo, out, Nn);
}

// Round 2
// 299.507 us; speedup vs baseline: 1.1197x; 1.1197x over previous
//
#include <hip/hip_runtime.h>
#include <math.h>

#define IN_DIM 256
#define OUT_DIM 128
#define NH 8
#define HD 16
#define GH 16
#define TBL 1024
#define LOG2E 1.44269504f
// R13: CSR build replaced by fixed-capacity row buckets.
//  - deg histogram pass (800k device atomics) DELETED
//  - scan_onepass dispatch DELETED (start = n*RCAP analytically)
//  - scatter writes final (col,u) directly: one atomic pass total
//  - scatter fused into qkv dispatch as tail blocks (atomic pipe overlaps
//    LDS/MFMA pipes); fallback to separate dispatch if ws too small.
// RCAP=64: rows ~ Poisson(16); P(any row >= 45) ~ 1e-4, P(>=64) ~ 1e-13.
// fused_node clamps to RCAP so pathological overflow degrades, not corrupts.
#define DPAD 32
#define RCAP 64

typedef __attribute__((ext_vector_type(8))) short short8;
typedef __attribute__((ext_vector_type(4))) float floatx4;

// ---------------- bf16 helpers (RNE) ----------------
__device__ __forceinline__ unsigned short f2bf(float f) {
    union { float f; unsigned u; } v; v.f = f;
    unsigned r = v.u + 0x7fffu + ((v.u >> 16) & 1u);
    return (unsigned short)(r >> 16);
}
__device__ __forceinline__ float bf2f(unsigned short h) {
    union { unsigned u; float f; } v; v.u = ((unsigned)h) << 16;
    return v.f;
}
__device__ __forceinline__ void split1(float f, unsigned short& h, unsigned short& l) {
    h = f2bf(f);
    l = f2bf(f - bf2f(h));
}
__device__ __forceinline__ float bflo(unsigned u) { return __uint_as_float(u << 16); }
__device__ __forceinline__ float bfhi(unsigned u) { return __uint_as_float(u & 0xffff0000u); }

// ---------------- prep_all: split x, split Wq/Wk/Wv/Wo, geo table, zero cnt ----------------
__global__ __launch_bounds__(256) void prep_all_kernel(
    const float* __restrict__ x, const float* __restrict__ Wq, const float* __restrict__ Wk,
    const float* __restrict__ Wv, const float* __restrict__ Wo,
    unsigned short* __restrict__ xh, unsigned short* __restrict__ xl,
    unsigned short* __restrict__ wh, unsigned short* __restrict__ wl,
    unsigned short* __restrict__ wo_h, unsigned short* __restrict__ wo_l,
    const float* __restrict__ Wg1, const float* __restrict__ bg1,
    const float* __restrict__ Wg2, const float* __restrict__ bg2,
    float* __restrict__ tbl, int* __restrict__ cnt,
    int n4x, int Nzero, int nsplit, int nwm, int nwo, int ngeo, int ndegz) {
    int bx = blockIdx.x;
    int t = threadIdx.x;

    if (bx < nsplit) {                       // split x
        int i = bx * 256 + t;
        if (i >= n4x) return;
        float4 f = ((const float4*)x)[i];
        ushort4 h, l;
        split1(f.x, h.x, l.x); split1(f.y, h.y, l.y);
        split1(f.z, h.z, l.z); split1(f.w, h.w, l.w);
        ((ushort4*)xh)[i] = h;
        ((ushort4*)xl)[i] = l;
        return;
    }
    bx -= nsplit;
    if (bx < 3 * nwm) {                      // split Wq/Wk/Wv
        int m = bx / nwm;
        int i = (bx - m * nwm) * 256 + t;
        if (i >= (OUT_DIM * IN_DIM) / 4) return;
        const float* W = (m == 0) ? Wq : (m == 1) ? Wk : Wv;
        float4 f = ((const float4*)W)[i];
        ushort4 h, l;
        split1(f.x, h.x, l.x); split1(f.y, h.y, l.y);
        split1(f.z, h.z, l.z); split1(f.w, h.w, l.w);
        size_t base = (size_t)m * (OUT_DIM * IN_DIM) / 4;
        ((ushort4*)wh)[base + i] = h;
        ((ushort4*)wl)[base + i] = l;
        return;
    }
    bx -= 3 * nwm;
    if (bx < nwo) {                          // split Wo
        int i = bx * 256 + t;
        if (i >= (OUT_DIM * OUT_DIM) / 4) return;
        float4 f = ((const float4*)Wo)[i];
        ushort4 h, l;
        split1(f.x, h.x, l.x); split1(f.y, h.y, l.y);
        split1(f.z, h.z, l.z); split1(f.w, h.w, l.w);
        ((ushort4*)wo_h)[i] = h;
        ((ushort4*)wo_l)[i] = l;
        return;
    }
    bx -= nwo;
    if (bx < ngeo) {                         // geo bias table (log2-domain)
        int i = bx * 256 + t;
        if (i >= TBL) return;
        float d = (float)i * (6.0f / (float)(TBL - 1));
        float rbf[GH];
#pragma unroll
        for (int j = 0; j < GH; ++j) {
            float c = 0.4f * (float)j;
            float tt = d - c;
            rbf[j] = __expf(-tt * tt);
        }
        float hid[GH];
#pragma unroll
        for (int j = 0; j < GH; ++j) {
            float acc = bg1[j];
#pragma unroll
            for (int kk = 0; kk < GH; ++kk) acc += rbf[kk] * Wg1[j * GH + kk];
            hid[j] = fmaxf(acc, 0.0f);
        }
#pragma unroll
        for (int h = 0; h < NH; ++h) {
            float acc = bg2[h];
#pragma unroll
            for (int j = 0; j < GH; ++j) acc += hid[j] * Wg2[h * GH + j];
            tbl[i * NH + h] = acc * LOG2E;
        }
        return;
    }
    bx -= ngeo;
    if (bx < ndegz) {                        // zero cnt region (int4)
        int idx4 = (bx * 256 + t) * 4;
        if (idx4 + 3 < Nzero) {
            *(int4*)(cnt + idx4) = make_int4(0, 0, 0, 0);
        } else {
#pragma unroll
            for (int j = 0; j < 4; ++j) if (idx4 + j < Nzero) cnt[idx4 + j] = 0;
        }
        return;
    }
}

// ---------------- scatter body: direct bucket placement, one atomic per edge ----------------
__device__ __forceinline__ void scatter_body(int i0, int stride, const int* __restrict__ ei,
                                             const float* __restrict__ edist, int* __restrict__ cnt,
                                             int2* __restrict__ bucket, int E_) {
    for (int e = i0; e < E_; e += stride) {
        int row = ei[e];
        int pos = atomicAdd(&cnt[row * DPAD], 1);
        float u = edist[e] * ((float)(TBL - 1) / 6.0f);
        u = fminf(fmaxf(u, 0.0f), (float)(TBL - 1));
        if (pos < RCAP) bucket[(size_t)row * RCAP + pos] = make_int2(ei[E_ + e], __float_as_int(u));
    }
}

// ---------------- qkv (128x128 tile) + optional fused scatter tail blocks ----------------
__global__ __launch_bounds__(256) void qkv_kernel(
    const unsigned short* __restrict__ xh, const unsigned short* __restrict__ xl,
    const unsigned short* __restrict__ wh, const unsigned short* __restrict__ wl,
    const float* __restrict__ bq, const float* __restrict__ bk, const float* __restrict__ bv,
    float* __restrict__ q, unsigned short* __restrict__ kb, unsigned short* __restrict__ vb,
    const int* __restrict__ ei, const float* __restrict__ edist,
    int* __restrict__ cnt, int2* __restrict__ bucket,
    int Nn, int E_, int nxb) {
    int bx = blockIdx.x;
    if (bx >= 3 * nxb) {                     // fused scatter tail (atomic pipe overlaps GEMM)
        int nb = gridDim.x - 3 * nxb;
        int i0 = (bx - 3 * nxb) * 256 + threadIdx.x;
        scatter_body(i0, nb * 256, ei, edist, cnt, bucket, E_);
        return;
    }
    const int wsel = bx / nxb;
    const int n0 = (bx - wsel * nxb) * 128;
    const unsigned short* W_h = wh + (size_t)wsel * (OUT_DIM * IN_DIM);
    const unsigned short* W_l = wl + (size_t)wsel * (OUT_DIM * IN_DIM);
    const float* bias = (wsel == 0) ? bq : (wsel == 1) ? bk : bv;
    const bool vpath = (wsel == 2);

    __shared__ unsigned short xh_s[128 * 40];
    __shared__ unsigned short xl_s[128 * 40];
    __shared__ unsigned short wh_s[128 * 40];
    __shared__ unsigned short wl_s[128 * 40];

    const int tid = threadIdx.x;
    const int w = tid >> 6;
    const int lane = tid & 63;
    const int ml = lane & 15;
    const int quad = lane >> 4;

    const int rows_valid = min(128, Nn - n0);

    floatx4 acc[2][8];
#pragma unroll
    for (int rr = 0; rr < 2; ++rr)
#pragma unroll
        for (int ct = 0; ct < 8; ++ct) acc[rr][ct] = (floatx4){0.f, 0.f, 0.f, 0.f};

    const short8 zero8 = {0, 0, 0, 0, 0, 0, 0, 0};

    for (int kc = 0; kc < IN_DIM; kc += 32) {
#pragma unroll
        for (int l = 0; l < 2; ++l) {
            int flat = tid + l * 256;        // 0..511 -> r 0..127, c 0..3 (8-short chunks)
            int r = flat >> 2, c = flat & 3;
            size_t gx = (size_t)(n0 + r) * IN_DIM + kc + c * 8;
            size_t gw = (size_t)r * IN_DIM + kc + c * 8;
            short8 vh = zero8;
            if (r < rows_valid) vh = *(const short8*)(xh + gx);
            *(short8*)(xh_s + r * 40 + c * 8) = vh;
            *(short8*)(wh_s + r * 40 + c * 8) = *(const short8*)(W_h + gw);
            if (vpath) {
                short8 vl = zero8;
                if (r < rows_valid) vl = *(const short8*)(xl + gx);
                *(short8*)(xl_s + r * 40 + c * 8) = vl;
                *(short8*)(wl_s + r * 40 + c * 8) = *(const short8*)(W_l + gw);
            }
        }
        __syncthreads();

        short8 ah0 = *(const short8*)(xh_s + (w * 32 + ml) * 40 + quad * 8);
        short8 ah1 = *(const short8*)(xh_s + (w * 32 + 16 + ml) * 40 + quad * 8);
        if (!vpath) {
#pragma unroll
            for (int ct = 0; ct < 8; ++ct) {
                short8 bh = *(const short8*)(wh_s + (ct * 16 + ml) * 40 + quad * 8);
                acc[0][ct] = __builtin_amdgcn_mfma_f32_16x16x32_bf16(ah0, bh, acc[0][ct], 0, 0, 0);
                acc[1][ct] = __builtin_amdgcn_mfma_f32_16x16x32_bf16(ah1, bh, acc[1][ct], 0, 0, 0);
            }
        } else {
            short8 al0 = *(const short8*)(xl_s + (w * 32 + ml) * 40 + quad * 8);
            short8 al1 = *(const short8*)(xl_s + (w * 32 + 16 + ml) * 40 + quad * 8);
#pragma unroll
            for (int ct = 0; ct < 8; ++ct) {
                short8 bh = *(const short8*)(wh_s + (ct * 16 + ml) * 40 + quad * 8);
                short8 bl = *(const short8*)(wl_s + (ct * 16 + ml) * 40 + quad * 8);
                acc[0][ct] = __builtin_amdgcn_mfma_f32_16x16x32_bf16(ah0, bh, acc[0][ct], 0, 0, 0);
                acc[0][ct] = __builtin_amdgcn_mfma_f32_16x16x32_bf16(al0, bh, acc[0][ct], 0, 0, 0);
                acc[0][ct] = __builtin_amdgcn_mfma_f32_16x16x32_bf16(ah0, bl, acc[0][ct], 0, 0, 0);
                acc[1][ct] = __builtin_amdgcn_mfma_f32_16x16x32_bf16(ah1, bh, acc[1][ct], 0, 0, 0);
                acc[1][ct] = __builtin_amdgcn_mfma_f32_16x16x32_bf16(al1, bh, acc[1][ct], 0, 0, 0);
                acc[1][ct] = __builtin_amdgcn_mfma_f32_16x16x32_bf16(ah1, bl, acc[1][ct], 0, 0, 0);
            }
        }
        __syncthreads();
    }

    if (wsel == 0) {
#pragma unroll
        for (int rr = 0; rr < 2; ++rr)
#pragma unroll
            for (int ct = 0; ct < 8; ++ct) {
                float bj = bias[ct * 16 + ml];
#pragma unroll
                for (int r = 0; r < 4; ++r) {
                    int grow = n0 + w * 32 + rr * 16 + quad * 4 + r;
                    if (grow < Nn) q[(size_t)grow * 128 + ct * 16 + ml] = acc[rr][ct][r] + bj;
                }
            }
    } else {
        unsigned short* ob = (wsel == 1) ? kb : vb;
#pragma unroll
        for (int rr = 0; rr < 2; ++rr)
#pragma unroll
            for (int ct = 0; ct < 8; ++ct) {
                float bj = bias[ct * 16 + ml];
#pragma unroll
                for (int r = 0; r < 4; ++r) {
                    int grow = n0 + w * 32 + rr * 16 + quad * 4 + r;
                    if (grow < Nn) ob[(size_t)grow * 128 + ct * 16 + ml] = f2bf(acc[rr][ct][r] + bj);
                }
            }
    }
}

// ---------------- standalone scatter (fallback when ws can't hold separate bucket) ----------------
__global__ __launch_bounds__(256) void scatter_kernel(const int* __restrict__ ei, const float* __restrict__ edist,
                                                      int* __restrict__ cnt, int2* __restrict__ bucket, int E_) {
    int i0 = blockIdx.x * 256 + threadIdx.x;
    scatter_body(i0, gridDim.x * 256, ei, edist, cnt, bucket, E_);
}

// ---------------- fused flash-style edge+node pass (bucket layout) ----------------
__global__ __launch_bounds__(256) void fused_node_kernel(
    const float* __restrict__ q, const unsigned short* __restrict__ kb,
    const unsigned short* __restrict__ vb, const int2* __restrict__ bucket,
    const float* __restrict__ tbl, const int* __restrict__ cnt,
    unsigned short* __restrict__ oh, unsigned short* __restrict__ ol, int Nn) {
    int lane = threadIdx.x & 63;
    int n = blockIdx.x * 4 + (threadIdx.x >> 6);
    if (n >= Nn) return;
    int g = lane >> 3;       // edge subgroup
    int h = lane & 7;        // head
    int dcnt = cnt[n * DPAD];
    if (dcnt > RCAP) dcnt = RCAP;
    int start = n * RCAP;
    int end = start + dcnt;

    float qf[16];
    {
        const float4* qp = (const float4*)(q + (size_t)n * 128 + h * 16);
#pragma unroll
        for (int j = 0; j < 4; ++j) {
            float4 t = qp[j];
            qf[j * 4 + 0] = t.x; qf[j * 4 + 1] = t.y;
            qf[j * 4 + 2] = t.z; qf[j * 4 + 3] = t.w;
        }
    }

    float l = 0.0f;
    float acc[16];
#pragma unroll
    for (int j = 0; j < 16; ++j) acc[j] = 0.0f;

#pragma unroll 2
    for (int base = start; base < end; base += 8) {
        int e = base + g;
        bool valid = (e < end);
        int ee = valid ? e : (end - 1);
        int2 np = bucket[ee];
        int col = np.x;
        float u = __int_as_float(np.y);

        const uint4* kp = (const uint4*)(kb + (size_t)col * 128 + h * 16);
        uint4 k0 = kp[0], k1 = kp[1];
        const uint4* vp = (const uint4*)(vb + (size_t)col * 128 + h * 16);
        uint4 v0 = vp[0], v1 = vp[1];

        unsigned kk[8] = {k0.x, k0.y, k0.z, k0.w, k1.x, k1.y, k1.z, k1.w};
        float d = 0.0f;
#pragma unroll
        for (int j = 0; j < 8; ++j) {
            d = fmaf(bflo(kk[j]), qf[2 * j], d);
            d = fmaf(bfhi(kk[j]), qf[2 * j + 1], d);
        }

        int i0 = min((int)u, TBL - 2);
        float fr = u - (float)i0;
        float t0 = tbl[i0 * NH + h];
        float t1 = tbl[i0 * NH + NH + h];
        float logit2 = fmaf(d, 0.25f * LOG2E, fmaf(fr, t1 - t0, t0));
        logit2 = fminf(logit2, 80.0f);
        if (!valid) logit2 = -1e30f;
        float p = __builtin_amdgcn_exp2f(logit2);

        l += p;
        unsigned vv[8] = {v0.x, v0.y, v0.z, v0.w, v1.x, v1.y, v1.z, v1.w};
#pragma unroll
        for (int j = 0; j < 8; ++j) {
            acc[2 * j]     = fmaf(p, bflo(vv[j]), acc[2 * j]);
            acc[2 * j + 1] = fmaf(p, bfhi(vv[j]), acc[2 * j + 1]);
        }
    }

#pragma unroll
    for (int off = 8; off < 64; off <<= 1) {
        l += __shfl_xor(l, off);
#pragma unroll
        for (int j = 0; j < 16; ++j) acc[j] += __shfl_xor(acc[j], off);
    }

    if (g == 0) {
        float inv = 1.0f / (l + 1e-12f);
        unsigned short hv[16], lv[16];
#pragma unroll
        for (int j = 0; j < 16; ++j) {
            float o = acc[j] * inv;
            split1(o, hv[j], lv[j]);
        }
        *(short8*)(oh + (size_t)n * 128 + h * 16) = *(short8*)hv;
        *(short8*)(oh + (size_t)n * 128 + h * 16 + 8) = *(short8*)(hv + 8);
        *(short8*)(ol + (size_t)n * 128 + h * 16) = *(short8*)lv;
        *(short8*)(ol + (size_t)n * 128 + h * 16 + 8) = *(short8*)(lv + 8);
    }
}

// ---------------- out GEMM via split-bf16 MFMA (K=128) ----------------
__global__ __launch_bounds__(256) void out_gemm_mfma_kernel(
    const unsigned short* __restrict__ oh, const unsigned short* __restrict__ ol,
    const unsigned short* __restrict__ wo_h, const unsigned short* __restrict__ wo_l,
    const float* __restrict__ bo, float* __restrict__ out, int Nn) {
    const int n0 = blockIdx.x * 64;

    __shared__ unsigned short xh_s[64 * 40];
    __shared__ unsigned short xl_s[64 * 40];
    __shared__ unsigned short wh_s[128 * 40];
    __shared__ unsigned short wl_s[128 * 40];

    const int tid = threadIdx.x;
    const int w = tid >> 6;
    const int lane = tid & 63;
    const int ml = lane & 15;
    const int quad = lane >> 4;

    const int rows_valid = min(64, Nn - n0);

    floatx4 acc[8];
#pragma unroll
    for (int ct = 0; ct < 8; ++ct) acc[ct] = (floatx4){0.f, 0.f, 0.f, 0.f};

    const short8 zero8 = {0, 0, 0, 0, 0, 0, 0, 0};

    for (int kc = 0; kc < OUT_DIM; kc += 32) {
        {
            int r = tid >> 2, c = tid & 3;
            short8 vh = zero8, vl = zero8;
            if (r < rows_valid) {
                size_t g = (size_t)(n0 + r) * OUT_DIM + kc + c * 8;
                vh = *(const short8*)(oh + g);
                vl = *(const short8*)(ol + g);
            }
            *(short8*)(xh_s + r * 40 + c * 8) = vh;
            *(short8*)(xl_s + r * 40 + c * 8) = vl;
        }
#pragma unroll
        for (int l = 0; l < 2; ++l) {
            int idx = tid + l * 256;
            int r = idx >> 2, c = idx & 3;
            size_t g = (size_t)r * OUT_DIM + kc + c * 8;
            *(short8*)(wh_s + r * 40 + c * 8) = *(const short8*)(wo_h + g);
            *(short8*)(wl_s + r * 40 + c * 8) = *(const short8*)(wo_l + g);
        }
        __syncthreads();

        short8 ah = *(const short8*)(xh_s + (w * 16 + ml) * 40 + quad * 8);
        short8 al = *(const short8*)(xl_s + (w * 16 + ml) * 40 + quad * 8);
#pragma unroll
        for (int ct = 0; ct < 8; ++ct) {
            short8 bh = *(const short8*)(wh_s + (ct * 16 + ml) * 40 + quad * 8);
            short8 bl = *(const short8*)(wl_s + (ct * 16 + ml) * 40 + quad * 8);
            acc[ct] = __builtin_amdgcn_mfma_f32_16x16x32_bf16(ah, bh, acc[ct], 0, 0, 0);
            acc[ct] = __builtin_amdgcn_mfma_f32_16x16x32_bf16(al, bh, acc[ct], 0, 0, 0);
            acc[ct] = __builtin_amdgcn_mfma_f32_16x16x32_bf16(ah, bl, acc[ct], 0, 0, 0);
        }
        __syncthreads();
    }

#pragma unroll
    for (int ct = 0; ct < 8; ++ct) {
        float bj = bo[ct * 16 + ml];
#pragma unroll
        for (int r = 0; r < 4; ++r) {
            int grow = n0 + w * 16 + quad * 4 + r;
            if (grow < Nn) out[(size_t)grow * 128 + ct * 16 + ml] = acc[ct][r] + bj;
        }
    }
}

extern "C" void kernel_launch(void* const* d_in, const int* in_sizes, int n_in,
                              void* d_out, int out_size, void* d_ws, size_t ws_size,
                              hipStream_t stream) {
    const float* x   = (const float*)d_in[0];
    const int* ei    = (const int*)d_in[1];
    const float* edist = (const float*)d_in[2];
    const float* Wq = (const float*)d_in[3];  const float* bq = (const float*)d_in[4];
    const float* Wk = (const float*)d_in[5];  const float* bk = (const float*)d_in[6];
    const float* Wv = (const float*)d_in[7];  const float* bv = (const float*)d_in[8];
    const float* Wo = (const float*)d_in[9];  const float* bo = (const float*)d_in[10];
    const float* Wg1 = (const float*)d_in[11]; const float* bg1 = (const float*)d_in[12];
    const float* Wg2 = (const float*)d_in[13]; const float* bg2 = (const float*)d_in[14];
    const int Nn = in_sizes[0] / IN_DIM;
    const int Ee = in_sizes[2];
    float* out = (float*)d_out;

    char* ws = (char*)d_ws;
    size_t off = 0;
    auto alloc = [&](size_t bytes) -> char* {
        char* p = ws + off;
        off += (bytes + 255) & ~(size_t)255;
        return p;
    };
    float* q  = (float*)alloc((size_t)Nn * 128 * 4);
    unsigned short* kbuf = (unsigned short*)alloc((size_t)Nn * 128 * 2);
    unsigned short* vbuf = (unsigned short*)alloc((size_t)Nn * 128 * 2);
    char* xlblock = alloc((size_t)Nn * IN_DIM * 2);
    unsigned short* o_hi = (unsigned short*)alloc((size_t)Nn * 128 * 2);
    unsigned short* o_lo = (unsigned short*)alloc((size_t)Nn * 128 * 2);
    float* geot = (float*)alloc((size_t)TBL * 8 * 4);
    int* cnt      = (int*)alloc((size_t)Nn * DPAD * 4);   // padded counters (cnt @ i*DPAD)
    unsigned short* wh_all = (unsigned short*)alloc((size_t)3 * OUT_DIM * IN_DIM * 2);
    unsigned short* wl_all = (unsigned short*)alloc((size_t)3 * OUT_DIM * IN_DIM * 2);
    unsigned short* wo_h = (unsigned short*)alloc((size_t)OUT_DIM * OUT_DIM * 2);
    unsigned short* wo_l = (unsigned short*)alloc((size_t)OUT_DIM * OUT_DIM * 2);
    int2* bucket_sep = (int2*)alloc((size_t)Nn * RCAP * 8);   // 25.6 MB, only if ws allows

    // If ws holds the separate bucket, fuse scatter into the qkv dispatch
    // (atomic pipe overlaps GEMM pipes). Otherwise overlay bucket on the
    // dead xl region (exactly Nn*512 B) and run scatter as its own dispatch
    // after qkv (xl is read by qkv's v-path, so no overlap then).
    const bool fuse_scat = (off <= ws_size);
    int2* bucket = fuse_scat ? bucket_sep : (int2*)xlblock;

    unsigned short* xh = (unsigned short*)d_out;       // rewritten by final GEMM
    unsigned short* xl = (unsigned short*)xlblock;

    // --- dispatch 1: prep_all ---
    int n4x = Nn * IN_DIM / 4;
    int nsplit = (n4x + 255) / 256;
    int nwm = ((OUT_DIM * IN_DIM / 4) + 255) / 256;
    int nwo = ((OUT_DIM * OUT_DIM / 4) + 255) / 256;
    int ngeo = (TBL + 255) / 256;
    int Nzero = Nn * DPAD;
    int ndegz = (Nzero + 1023) / 1024;
    int gprep = nsplit + 3 * nwm + nwo + ngeo + ndegz;
    prep_all_kernel<<<gprep, 256, 0, stream>>>(
        x, Wq, Wk, Wv, Wo, xh, xl, wh_all, wl_all, wo_h, wo_l,
        Wg1, bg1, Wg2, bg2, geot, cnt, n4x, Nzero, nsplit, nwm, nwo, ngeo, ndegz);

    // --- dispatch 2: qkv (128-row tiles) [+ fused scatter tail blocks] ---
    int nxb = (Nn + 127) / 128;
    if (fuse_scat) {
        qkv_kernel<<<3 * nxb + 2048, 256, 0, stream>>>(
            xh, xl, wh_all, wl_all, bq, bk, bv, q, kbuf, vbuf,
            ei, edist, cnt, bucket, Nn, Ee, nxb);
    } else {
        qkv_kernel<<<3 * nxb, 256, 0, stream>>>(
            xh, xl, wh_all, wl_all, bq, bk, bv, q, kbuf, vbuf,
            ei, edist, cnt, bucket, Nn, Ee, nxb);
        scatter_kernel<<<1024, 256, 0, stream>>>(ei, edist, cnt, bucket, Ee);
    }

    // --- dispatch 3: fused edge+node ---
    fused_node_kernel<<<(Nn + 3) / 4, 256, 0, stream>>>(q, kbuf, vbuf, bucket, geot, cnt, o_hi, o_lo, Nn);

    // --- dispatch 4: out GEMM ---
    out_gemm_mfma_kernel<<<(Nn + 63) / 64, 256, 0, stream>>>(o_hi, o_lo, wo_h, wo_l, bo, out, Nn);
}

// Round 3
// 289.294 us; speedup vs baseline: 1.1592x; 1.0353x over previous
//
#include <hip/hip_runtime.h>
#include <math.h>

#define IN_DIM 256
#define OUT_DIM 128
#define NH 8
#define HD 16
#define GH 16
#define TBL 1024
#define LOG2E 1.44269504f
// R14: two-phase bin sort replaces the 800k device-scope atomics.
// R12/R13 evidence: device atomic throughput ~5.5/cy chip-wide regardless of
// line padding -> only reducing atomic COUNT helps.
//  - phase1 (fused at FRONT of qkv grid, overlaps GEMM): 4096-edge blocks,
//    LDS histogram over row-bins (bin=row>>7), ONE global atomic per
//    (block,nonzero-bin) ~76k total, scatter packed (col|rowrel,u) to bin segs.
//  - phase2 (391 blocks): LDS-rank bin edges into per-row RCAP buckets,
//    write cnt[row] directly. Zero global atomics.
//  - o stored f32 (split to hi/lo inside out_gemm): -25.6MB HBM, same math.
#define RCAP 64
#define BCAP 2560   // bin capacity: Poisson(2048) per 128-row bin, +11 sigma

typedef __attribute__((ext_vector_type(8))) short short8;
typedef __attribute__((ext_vector_type(4))) float floatx4;

// ---------------- bf16 helpers (RNE) ----------------
__device__ __forceinline__ unsigned short f2bf(float f) {
    union { float f; unsigned u; } v; v.f = f;
    unsigned r = v.u + 0x7fffu + ((v.u >> 16) & 1u);
    return (unsigned short)(r >> 16);
}
__device__ __forceinline__ float bf2f(unsigned short h) {
    union { unsigned u; float f; } v; v.u = ((unsigned)h) << 16;
    return v.f;
}
__device__ __forceinline__ void split1(float f, unsigned short& h, unsigned short& l) {
    h = f2bf(f);
    l = f2bf(f - bf2f(h));
}
__device__ __forceinline__ float bflo(unsigned u) { return __uint_as_float(u << 16); }
__device__ __forceinline__ float bfhi(unsigned u) { return __uint_as_float(u & 0xffff0000u); }

// ---------------- prep_all: split x, split Wq/Wk/Wv/Wo, geo table, zero gbin ----------------
__global__ __launch_bounds__(256) void prep_all_kernel(
    const float* __restrict__ x, const float* __restrict__ Wq, const float* __restrict__ Wk,
    const float* __restrict__ Wv, const float* __restrict__ Wo,
    unsigned short* __restrict__ xh, unsigned short* __restrict__ xl,
    unsigned short* __restrict__ wh, unsigned short* __restrict__ wl,
    unsigned short* __restrict__ wo_h, unsigned short* __restrict__ wo_l,
    const float* __restrict__ Wg1, const float* __restrict__ bg1,
    const float* __restrict__ Wg2, const float* __restrict__ bg2,
    float* __restrict__ tbl, int* __restrict__ gbin,
    int n4x, int nbins, int nsplit, int nwm, int nwo, int ngeo) {
    int bx = blockIdx.x;
    int t = threadIdx.x;

    if (bx < nsplit) {                       // split x
        int i = bx * 256 + t;
        if (i >= n4x) return;
        float4 f = ((const float4*)x)[i];
        ushort4 h, l;
        split1(f.x, h.x, l.x); split1(f.y, h.y, l.y);
        split1(f.z, h.z, l.z); split1(f.w, h.w, l.w);
        ((ushort4*)xh)[i] = h;
        ((ushort4*)xl)[i] = l;
        return;
    }
    bx -= nsplit;
    if (bx < 3 * nwm) {                      // split Wq/Wk/Wv
        int m = bx / nwm;
        int i = (bx - m * nwm) * 256 + t;
        if (i >= (OUT_DIM * IN_DIM) / 4) return;
        const float* W = (m == 0) ? Wq : (m == 1) ? Wk : Wv;
        float4 f = ((const float4*)W)[i];
        ushort4 h, l;
        split1(f.x, h.x, l.x); split1(f.y, h.y, l.y);
        split1(f.z, h.z, l.z); split1(f.w, h.w, l.w);
        size_t base = (size_t)m * (OUT_DIM * IN_DIM) / 4;
        ((ushort4*)wh)[base + i] = h;
        ((ushort4*)wl)[base + i] = l;
        return;
    }
    bx -= 3 * nwm;
    if (bx < nwo) {                          // split Wo
        int i = bx * 256 + t;
        if (i >= (OUT_DIM * OUT_DIM) / 4) return;
        float4 f = ((const float4*)Wo)[i];
        ushort4 h, l;
        split1(f.x, h.x, l.x); split1(f.y, h.y, l.y);
        split1(f.z, h.z, l.z); split1(f.w, h.w, l.w);
        ((ushort4*)wo_h)[i] = h;
        ((ushort4*)wo_l)[i] = l;
        return;
    }
    bx -= nwo;
    if (bx < ngeo) {                         // geo bias table (log2-domain)
        int i = bx * 256 + t;
        if (i >= TBL) return;
        float d = (float)i * (6.0f / (float)(TBL - 1));
        float rbf[GH];
#pragma unroll
        for (int j = 0; j < GH; ++j) {
            float c = 0.4f * (float)j;
            float tt = d - c;
            rbf[j] = __expf(-tt * tt);
        }
        float hid[GH];
#pragma unroll
        for (int j = 0; j < GH; ++j) {
            float acc = bg1[j];
#pragma unroll
            for (int kk = 0; kk < GH; ++kk) acc += rbf[kk] * Wg1[j * GH + kk];
            hid[j] = fmaxf(acc, 0.0f);
        }
#pragma unroll
        for (int h = 0; h < NH; ++h) {
            float acc = bg2[h];
#pragma unroll
            for (int j = 0; j < GH; ++j) acc += hid[j] * Wg2[h * GH + j];
            tbl[i * NH + h] = acc * LOG2E;
        }
        return;
    }
    // last block: zero gbin
    for (int i = t; i < nbins; i += 256) gbin[i] = 0;
}

// ---------------- qkv (128x128 tile) + phase-1 bin scatter at grid FRONT ----------------
__global__ __launch_bounds__(256) void qkv_kernel(
    const unsigned short* __restrict__ xh, const unsigned short* __restrict__ xl,
    const unsigned short* __restrict__ wh, const unsigned short* __restrict__ wl,
    const float* __restrict__ bq, const float* __restrict__ bk, const float* __restrict__ bv,
    float* __restrict__ q, unsigned short* __restrict__ kb, unsigned short* __restrict__ vb,
    const int* __restrict__ ei, const float* __restrict__ edist,
    int* __restrict__ gbin, int2* __restrict__ binbuf,
    int Nn, int E_, int nxb, int nb1, int nbins) {
    __shared__ unsigned short xh_s[128 * 40];
    __shared__ unsigned short xl_s[128 * 40];
    __shared__ unsigned short wh_s[128 * 40];
    __shared__ unsigned short wl_s[128 * 40];

    const int tid = threadIdx.x;
    int bx = blockIdx.x;

    if (bx < nb1) {
        // ---- phase 1: bin scatter (runs first -> overlaps GEMM blocks) ----
        int* hist = (int*)xh_s;              // reuse LDS (nbins*4 <= 10KB)
        const int e0 = bx * 4096;
        for (int b = tid; b < nbins; b += 256) hist[b] = 0;
        __syncthreads();
#pragma unroll
        for (int i = 0; i < 16; ++i) {
            int e = e0 + tid + i * 256;
            if (e < E_) atomicAdd(&hist[ei[e] >> 7], 1);
        }
        __syncthreads();
        for (int b = tid; b < nbins; b += 256) {
            int h = hist[b];
            int base = 0;
            if (h) base = atomicAdd(&gbin[b], h);   // only ~nonzero-bins global atomics
            hist[b] = base;                          // hist becomes running cursor
        }
        __syncthreads();
#pragma unroll
        for (int i = 0; i < 16; ++i) {
            int e = e0 + tid + i * 256;
            if (e < E_) {
                int row = ei[e];
                int bin = row >> 7;
                int r = atomicAdd(&hist[bin], 1);    // absolute pos within bin
                float u = edist[e] * ((float)(TBL - 1) / 6.0f);
                u = fminf(fmaxf(u, 0.0f), (float)(TBL - 1));
                if (r < BCAP)
                    binbuf[(size_t)bin * BCAP + r] =
                        make_int2((ei[E_ + e] & 0x1FFFF) | ((row & 127) << 17), __float_as_int(u));
            }
        }
        return;
    }
    bx -= nb1;

    const int wsel = bx / nxb;
    const int n0 = (bx - wsel * nxb) * 128;
    const unsigned short* W_h = wh + (size_t)wsel * (OUT_DIM * IN_DIM);
    const unsigned short* W_l = wl + (size_t)wsel * (OUT_DIM * IN_DIM);
    const float* bias = (wsel == 0) ? bq : (wsel == 1) ? bk : bv;
    const bool vpath = (wsel == 2);

    const int w = tid >> 6;
    const int lane = tid & 63;
    const int ml = lane & 15;
    const int quad = lane >> 4;

    const int rows_valid = min(128, Nn - n0);

    floatx4 acc[2][8];
#pragma unroll
    for (int rr = 0; rr < 2; ++rr)
#pragma unroll
        for (int ct = 0; ct < 8; ++ct) acc[rr][ct] = (floatx4){0.f, 0.f, 0.f, 0.f};

    const short8 zero8 = {0, 0, 0, 0, 0, 0, 0, 0};

    for (int kc = 0; kc < IN_DIM; kc += 32) {
#pragma unroll
        for (int l = 0; l < 2; ++l) {
            int flat = tid + l * 256;        // 0..511 -> r 0..127, c 0..3 (8-short chunks)
            int r = flat >> 2, c = flat & 3;
            size_t gx = (size_t)(n0 + r) * IN_DIM + kc + c * 8;
            size_t gw = (size_t)r * IN_DIM + kc + c * 8;
            short8 vh = zero8;
            if (r < rows_valid) vh = *(const short8*)(xh + gx);
            *(short8*)(xh_s + r * 40 + c * 8) = vh;
            *(short8*)(wh_s + r * 40 + c * 8) = *(const short8*)(W_h + gw);
            if (vpath) {
                short8 vl = zero8;
                if (r < rows_valid) vl = *(const short8*)(xl + gx);
                *(short8*)(xl_s + r * 40 + c * 8) = vl;
                *(short8*)(wl_s + r * 40 + c * 8) = *(const short8*)(W_l + gw);
            }
        }
        __syncthreads();

        short8 ah0 = *(const short8*)(xh_s + (w * 32 + ml) * 40 + quad * 8);
        short8 ah1 = *(const short8*)(xh_s + (w * 32 + 16 + ml) * 40 + quad * 8);
        if (!vpath) {
#pragma unroll
            for (int ct = 0; ct < 8; ++ct) {
                short8 bh = *(const short8*)(wh_s + (ct * 16 + ml) * 40 + quad * 8);
                acc[0][ct] = __builtin_amdgcn_mfma_f32_16x16x32_bf16(ah0, bh, acc[0][ct], 0, 0, 0);
                acc[1][ct] = __builtin_amdgcn_mfma_f32_16x16x32_bf16(ah1, bh, acc[1][ct], 0, 0, 0);
            }
        } else {
            short8 al0 = *(const short8*)(xl_s + (w * 32 + ml) * 40 + quad * 8);
            short8 al1 = *(const short8*)(xl_s + (w * 32 + 16 + ml) * 40 + quad * 8);
#pragma unroll
            for (int ct = 0; ct < 8; ++ct) {
                short8 bh = *(const short8*)(wh_s + (ct * 16 + ml) * 40 + quad * 8);
                short8 bl = *(const short8*)(wl_s + (ct * 16 + ml) * 40 + quad * 8);
                acc[0][ct] = __builtin_amdgcn_mfma_f32_16x16x32_bf16(ah0, bh, acc[0][ct], 0, 0, 0);
                acc[0][ct] = __builtin_amdgcn_mfma_f32_16x16x32_bf16(al0, bh, acc[0][ct], 0, 0, 0);
                acc[0][ct] = __builtin_amdgcn_mfma_f32_16x16x32_bf16(ah0, bl, acc[0][ct], 0, 0, 0);
                acc[1][ct] = __builtin_amdgcn_mfma_f32_16x16x32_bf16(ah1, bh, acc[1][ct], 0, 0, 0);
                acc[1][ct] = __builtin_amdgcn_mfma_f32_16x16x32_bf16(al1, bh, acc[1][ct], 0, 0, 0);
                acc[1][ct] = __builtin_amdgcn_mfma_f32_16x16x32_bf16(ah1, bl, acc[1][ct], 0, 0, 0);
            }
        }
        __syncthreads();
    }

    if (wsel == 0) {
#pragma unroll
        for (int rr = 0; rr < 2; ++rr)
#pragma unroll
            for (int ct = 0; ct < 8; ++ct) {
                float bj = bias[ct * 16 + ml];
#pragma unroll
                for (int r = 0; r < 4; ++r) {
                    int grow = n0 + w * 32 + rr * 16 + quad * 4 + r;
                    if (grow < Nn) q[(size_t)grow * 128 + ct * 16 + ml] = acc[rr][ct][r] + bj;
                }
            }
    } else {
        unsigned short* ob = (wsel == 1) ? kb : vb;
#pragma unroll
        for (int rr = 0; rr < 2; ++rr)
#pragma unroll
            for (int ct = 0; ct < 8; ++ct) {
                float bj = bias[ct * 16 + ml];
#pragma unroll
                for (int r = 0; r < 4; ++r) {
                    int grow = n0 + w * 32 + rr * 16 + quad * 4 + r;
                    if (grow < Nn) ob[(size_t)grow * 128 + ct * 16 + ml] = f2bf(acc[rr][ct][r] + bj);
                }
            }
    }
}

// ---------------- phase 2: bin -> per-row buckets (LDS atomics only) ----------------
__global__ __launch_bounds__(256) void bin2bucket_kernel(
    const int2* __restrict__ binbuf, const int* __restrict__ gbin,
    int2* __restrict__ bucket, int* __restrict__ cnt, int Nn) {
    __shared__ int rcnt[128];
    const int bin = blockIdx.x;
    const int t = threadIdx.x;
    if (t < 128) rcnt[t] = 0;
    __syncthreads();
    int nb = gbin[bin];
    if (nb > BCAP) nb = BCAP;
    const int row0 = bin << 7;
    for (int i = t; i < nb; i += 256) {
        int2 p = binbuf[(size_t)bin * BCAP + i];
        int rowrel = (p.x >> 17) & 127;
        int col = p.x & 0x1FFFF;
        int r = atomicAdd(&rcnt[rowrel], 1);
        if (r < RCAP) bucket[(size_t)(row0 + rowrel) * RCAP + r] = make_int2(col, p.y);
    }
    __syncthreads();
    if (t < 128 && row0 + t < Nn) cnt[row0 + t] = min(rcnt[t], RCAP);
}

// ---------------- fused flash-style edge+node pass (bucket layout, f32 output) ----------------
__global__ __launch_bounds__(256) void fused_node_kernel(
    const float* __restrict__ q, const unsigned short* __restrict__ kb,
    const unsigned short* __restrict__ vb, const int2* __restrict__ bucket,
    const float* __restrict__ tbl, const int* __restrict__ cnt,
    float* __restrict__ o, int Nn) {
    int lane = threadIdx.x & 63;
    int n = blockIdx.x * 4 + (threadIdx.x >> 6);
    if (n >= Nn) return;
    int g = lane >> 3;       // edge subgroup
    int h = lane & 7;        // head
    int dcnt = cnt[n];
    int start = n * RCAP;
    int end = start + dcnt;

    float qf[16];
    {
        const float4* qp = (const float4*)(q + (size_t)n * 128 + h * 16);
#pragma unroll
        for (int j = 0; j < 4; ++j) {
            float4 t = qp[j];
            qf[j * 4 + 0] = t.x; qf[j * 4 + 1] = t.y;
            qf[j * 4 + 2] = t.z; qf[j * 4 + 3] = t.w;
        }
    }

    float l = 0.0f;
    float acc[16];
#pragma unroll
    for (int j = 0; j < 16; ++j) acc[j] = 0.0f;

#pragma unroll 2
    for (int base = start; base < end; base += 8) {
        int e = base + g;
        bool valid = (e < end);
        int ee = valid ? e : (end - 1);
        int2 np = bucket[ee];
        int col = np.x;
        float u = __int_as_float(np.y);

        const uint4* kp = (const uint4*)(kb + (size_t)col * 128 + h * 16);
        uint4 k0 = kp[0], k1 = kp[1];
        const uint4* vp = (const uint4*)(vb + (size_t)col * 128 + h * 16);
        uint4 v0 = vp[0], v1 = vp[1];

        unsigned kk[8] = {k0.x, k0.y, k0.z, k0.w, k1.x, k1.y, k1.z, k1.w};
        float d = 0.0f;
#pragma unroll
        for (int j = 0; j < 8; ++j) {
            d = fmaf(bflo(kk[j]), qf[2 * j], d);
            d = fmaf(bfhi(kk[j]), qf[2 * j + 1], d);
        }

        int i0 = min((int)u, TBL - 2);
        float fr = u - (float)i0;
        float t0 = tbl[i0 * NH + h];
        float t1 = tbl[i0 * NH + NH + h];
        float logit2 = fmaf(d, 0.25f * LOG2E, fmaf(fr, t1 - t0, t0));
        logit2 = fminf(logit2, 80.0f);
        if (!valid) logit2 = -1e30f;
        float p = __builtin_amdgcn_exp2f(logit2);

        l += p;
        unsigned vv[8] = {v0.x, v0.y, v0.z, v0.w, v1.x, v1.y, v1.z, v1.w};
#pragma unroll
        for (int j = 0; j < 8; ++j) {
            acc[2 * j]     = fmaf(p, bflo(vv[j]), acc[2 * j]);
            acc[2 * j + 1] = fmaf(p, bfhi(vv[j]), acc[2 * j + 1]);
        }
    }

#pragma unroll
    for (int off = 8; off < 64; off <<= 1) {
        l += __shfl_xor(l, off);
#pragma unroll
        for (int j = 0; j < 16; ++j) acc[j] += __shfl_xor(acc[j], off);
    }

    if (g == 0) {
        float inv = 1.0f / (l + 1e-12f);
        float4* op = (float4*)(o + (size_t)n * 128 + h * 16);
#pragma unroll
        for (int j = 0; j < 4; ++j) {
            float4 t;
            t.x = acc[j * 4 + 0] * inv; t.y = acc[j * 4 + 1] * inv;
            t.z = acc[j * 4 + 2] * inv; t.w = acc[j * 4 + 3] * inv;
            op[j] = t;
        }
    }
}

// ---------------- out GEMM via split-bf16 MFMA (K=128), in-kernel split of f32 o ----------------
__global__ __launch_bounds__(256) void out_gemm_mfma_kernel(
    const float* __restrict__ o,
    const unsigned short* __restrict__ wo_h, const unsigned short* __restrict__ wo_l,
    const float* __restrict__ bo, float* __restrict__ out, int Nn) {
    const int n0 = blockIdx.x * 64;

    __shared__ unsigned short xh_s[64 * 40];
    __shared__ unsigned short xl_s[64 * 40];
    __shared__ unsigned short wh_s[128 * 40];
    __shared__ unsigned short wl_s[128 * 40];

    const int tid = threadIdx.x;
    const int w = tid >> 6;
    const int lane = tid & 63;
    const int ml = lane & 15;
    const int quad = lane >> 4;

    const int rows_valid = min(64, Nn - n0);

    floatx4 acc[8];
#pragma unroll
    for (int ct = 0; ct < 8; ++ct) acc[ct] = (floatx4){0.f, 0.f, 0.f, 0.f};

    for (int kc = 0; kc < OUT_DIM; kc += 32) {
        {
            int r = tid >> 2, c = tid & 3;
            unsigned short hv[8], lv[8];
            if (r < rows_valid) {
                const float* src = o + (size_t)(n0 + r) * OUT_DIM + kc + c * 8;
#pragma unroll
                for (int j = 0; j < 8; ++j) split1(src[j], hv[j], lv[j]);
            } else {
#pragma unroll
                for (int j = 0; j < 8; ++j) { hv[j] = 0; lv[j] = 0; }
            }
            *(short8*)(xh_s + r * 40 + c * 8) = *(short8*)hv;
            *(short8*)(xl_s + r * 40 + c * 8) = *(short8*)lv;
        }
#pragma unroll
        for (int l = 0; l < 2; ++l) {
            int idx = tid + l * 256;
            int r = idx >> 2, c = idx & 3;
            size_t g = (size_t)r * OUT_DIM + kc + c * 8;
            *(short8*)(wh_s + r * 40 + c * 8) = *(const short8*)(wo_h + g);
            *(short8*)(wl_s + r * 40 + c * 8) = *(const short8*)(wo_l + g);
        }
        __syncthreads();

        short8 ah = *(const short8*)(xh_s + (w * 16 + ml) * 40 + quad * 8);
        short8 al = *(const short8*)(xl_s + (w * 16 + ml) * 40 + quad * 8);
#pragma unroll
        for (int ct = 0; ct < 8; ++ct) {
            short8 bh = *(const short8*)(wh_s + (ct * 16 + ml) * 40 + quad * 8);
            short8 bl = *(const short8*)(wl_s + (ct * 16 + ml) * 40 + quad * 8);
            acc[ct] = __builtin_amdgcn_mfma_f32_16x16x32_bf16(ah, bh, acc[ct], 0, 0, 0);
            acc[ct] = __builtin_amdgcn_mfma_f32_16x16x32_bf16(al, bh, acc[ct], 0, 0, 0);
            acc[ct] = __builtin_amdgcn_mfma_f32_16x16x32_bf16(ah, bl, acc[ct], 0, 0, 0);
        }
        __syncthreads();
    }

#pragma unroll
    for (int ct = 0; ct < 8; ++ct) {
        float bj = bo[ct * 16 + ml];
#pragma unroll
        for (int r = 0; r < 4; ++r) {
            int grow = n0 + w * 16 + quad * 4 + r;
            if (grow < Nn) out[(size_t)grow * 128 + ct * 16 + ml] = acc[ct][r] + bj;
        }
    }
}

extern "C" void kernel_launch(void* const* d_in, const int* in_sizes, int n_in,
                              void* d_out, int out_size, void* d_ws, size_t ws_size,
                              hipStream_t stream) {
    const float* x   = (const float*)d_in[0];
    const int* ei    = (const int*)d_in[1];
    const float* edist = (const float*)d_in[2];
    const float* Wq = (const float*)d_in[3];  const float* bq = (const float*)d_in[4];
    const float* Wk = (const float*)d_in[5];  const float* bk = (const float*)d_in[6];
    const float* Wv = (const float*)d_in[7];  const float* bv = (const float*)d_in[8];
    const float* Wo = (const float*)d_in[9];  const float* bo = (const float*)d_in[10];
    const float* Wg1 = (const float*)d_in[11]; const float* bg1 = (const float*)d_in[12];
    const float* Wg2 = (const float*)d_in[13]; const float* bg2 = (const float*)d_in[14];
    const int Nn = in_sizes[0] / IN_DIM;
    const int Ee = in_sizes[2];
    float* out = (float*)d_out;

    char* ws = (char*)d_ws;
    size_t off = 0;
    auto alloc = [&](size_t bytes) -> char* {
        char* p = ws + off;
        off += (bytes + 255) & ~(size_t)255;
        return p;
    };
    float* q  = (float*)alloc((size_t)Nn * 128 * 4);
    unsigned short* kbuf = (unsigned short*)alloc((size_t)Nn * 128 * 2);
    unsigned short* vbuf = (unsigned short*)alloc((size_t)Nn * 128 * 2);
    char* xlblock = alloc((size_t)Nn * IN_DIM * 2);
    float* o = (float*)alloc((size_t)Nn * 128 * 4);       // f32 attention output; binbuf aliases it
    float* geot = (float*)alloc((size_t)TBL * 8 * 4);
    int* cnt = (int*)alloc((size_t)Nn * 4);
    int nbins = (Nn + 127) >> 7;
    int* gbin = (int*)alloc((size_t)nbins * 4);
    unsigned short* wh_all = (unsigned short*)alloc((size_t)3 * OUT_DIM * IN_DIM * 2);
    unsigned short* wl_all = (unsigned short*)alloc((size_t)3 * OUT_DIM * IN_DIM * 2);
    unsigned short* wo_h = (unsigned short*)alloc((size_t)OUT_DIM * OUT_DIM * 2);
    unsigned short* wo_l = (unsigned short*)alloc((size_t)OUT_DIM * OUT_DIM * 2);
    int2* bucket = (int2*)alloc((size_t)Nn * RCAP * 8);   // 25.6 MB

    // binbuf aliases o: 391*2560*8 = 8.0 MB <= Nn*512 B = 25.6 MB.
    // Lifetime: binbuf written in qkv dispatch (phase1), read in bin2bucket,
    // dead before fused_node writes o. No overlap.
    int2* binbuf = (int2*)o;

    unsigned short* xh = (unsigned short*)d_out;       // rewritten by final GEMM
    unsigned short* xl = (unsigned short*)xlblock;

    // --- dispatch 1: prep_all ---
    int n4x = Nn * IN_DIM / 4;
    int nsplit = (n4x + 255) / 256;
    int nwm = ((OUT_DIM * IN_DIM / 4) + 255) / 256;
    int nwo = ((OUT_DIM * OUT_DIM / 4) + 255) / 256;
    int ngeo = (TBL + 255) / 256;
    int gprep = nsplit + 3 * nwm + nwo + ngeo + 1;     // +1 block zeroes gbin
    prep_all_kernel<<<gprep, 256, 0, stream>>>(
        x, Wq, Wk, Wv, Wo, xh, xl, wh_all, wl_all, wo_h, wo_l,
        Wg1, bg1, Wg2, bg2, geot, gbin, n4x, nbins, nsplit, nwm, nwo, ngeo);

    // --- dispatch 2: [phase1 bin-scatter blocks first] + qkv GEMM blocks ---
    int nxb = (Nn + 127) / 128;
    int nb1 = (Ee + 4095) / 4096;
    qkv_kernel<<<nb1 + 3 * nxb, 256, 0, stream>>>(
        xh, xl, wh_all, wl_all, bq, bk, bv, q, kbuf, vbuf,
        ei, edist, gbin, binbuf, Nn, Ee, nxb, nb1, nbins);

    // --- dispatch 3: phase2 bin -> buckets (LDS atomics only) ---
    bin2bucket_kernel<<<nbins, 256, 0, stream>>>(binbuf, gbin, bucket, cnt, Nn);

    // --- dispatch 4: fused edge+node ---
    fused_node_kernel<<<(Nn + 3) / 4, 256, 0, stream>>>(q, kbuf, vbuf, bucket, geot, cnt, o, Nn);

    // --- dispatch 5: out GEMM ---
    out_gemm_mfma_kernel<<<(Nn + 63) / 64, 256, 0, stream>>>(o, wo_h, wo_l, bo, out, Nn);
}

// Round 4
// 270.721 us; speedup vs baseline: 1.2388x; 1.0686x over previous
//
#include <hip/hip_runtime.h>
#include <math.h>

#define IN_DIM 256
#define OUT_DIM 128
#define NH 8
#define HD 16
#define GH 16
#define TBL 1024
#define LOG2E 1.44269504f
// R15: occupancy + write-coalescing round.
//  - qkv/out_gemm: 512-thread blocks (8 waves, (rg,cg) wave mapping), acc
//    32 VGPR/thread, __launch_bounds__(512,4) -> 2+ blocks (16+ waves)/CU
//    vs measured 5.6 waves (R14 was latency-bound at 17% occupancy).
//  - bin2bucket v2: LDS rank + prefix + compact -> COALESCED bucket writes
//    (was 800k scattered 8B partial-line writes), emits CSR rowstart.
//  - fused_node: CSR indexing + next-tile bucket prefetch.
#define RCAP 64
#define BCAP 2560   // bin capacity: Poisson(2048) per 128-row bin, +11 sigma

typedef __attribute__((ext_vector_type(8))) short short8;
typedef __attribute__((ext_vector_type(4))) float floatx4;

// ---------------- bf16 helpers (RNE) ----------------
__device__ __forceinline__ unsigned short f2bf(float f) {
    union { float f; unsigned u; } v; v.f = f;
    unsigned r = v.u + 0x7fffu + ((v.u >> 16) & 1u);
    return (unsigned short)(r >> 16);
}
__device__ __forceinline__ float bf2f(unsigned short h) {
    union { unsigned u; float f; } v; v.u = ((unsigned)h) << 16;
    return v.f;
}
__device__ __forceinline__ void split1(float f, unsigned short& h, unsigned short& l) {
    h = f2bf(f);
    l = f2bf(f - bf2f(h));
}
__device__ __forceinline__ float bflo(unsigned u) { return __uint_as_float(u << 16); }
__device__ __forceinline__ float bfhi(unsigned u) { return __uint_as_float(u & 0xffff0000u); }

// ---------------- prep_all: split x, split Wq/Wk/Wv/Wo, geo table, zero gbin ----------------
__global__ __launch_bounds__(256) void prep_all_kernel(
    const float* __restrict__ x, const float* __restrict__ Wq, const float* __restrict__ Wk,
    const float* __restrict__ Wv, const float* __restrict__ Wo,
    unsigned short* __restrict__ xh, unsigned short* __restrict__ xl,
    unsigned short* __restrict__ wh, unsigned short* __restrict__ wl,
    unsigned short* __restrict__ wo_h, unsigned short* __restrict__ wo_l,
    const float* __restrict__ Wg1, const float* __restrict__ bg1,
    const float* __restrict__ Wg2, const float* __restrict__ bg2,
    float* __restrict__ tbl, int* __restrict__ gbin,
    int n4x, int nbins, int nsplit, int nwm, int nwo, int ngeo) {
    int bx = blockIdx.x;
    int t = threadIdx.x;

    if (bx < nsplit) {                       // split x
        int i = bx * 256 + t;
        if (i >= n4x) return;
        float4 f = ((const float4*)x)[i];
        ushort4 h, l;
        split1(f.x, h.x, l.x); split1(f.y, h.y, l.y);
        split1(f.z, h.z, l.z); split1(f.w, h.w, l.w);
        ((ushort4*)xh)[i] = h;
        ((ushort4*)xl)[i] = l;
        return;
    }
    bx -= nsplit;
    if (bx < 3 * nwm) {                      // split Wq/Wk/Wv
        int m = bx / nwm;
        int i = (bx - m * nwm) * 256 + t;
        if (i >= (OUT_DIM * IN_DIM) / 4) return;
        const float* W = (m == 0) ? Wq : (m == 1) ? Wk : Wv;
        float4 f = ((const float4*)W)[i];
        ushort4 h, l;
        split1(f.x, h.x, l.x); split1(f.y, h.y, l.y);
        split1(f.z, h.z, l.z); split1(f.w, h.w, l.w);
        size_t base = (size_t)m * (OUT_DIM * IN_DIM) / 4;
        ((ushort4*)wh)[base + i] = h;
        ((ushort4*)wl)[base + i] = l;
        return;
    }
    bx -= 3 * nwm;
    if (bx < nwo) {                          // split Wo
        int i = bx * 256 + t;
        if (i >= (OUT_DIM * OUT_DIM) / 4) return;
        float4 f = ((const float4*)Wo)[i];
        ushort4 h, l;
        split1(f.x, h.x, l.x); split1(f.y, h.y, l.y);
        split1(f.z, h.z, l.z); split1(f.w, h.w, l.w);
        ((ushort4*)wo_h)[i] = h;
        ((ushort4*)wo_l)[i] = l;
        return;
    }
    bx -= nwo;
    if (bx < ngeo) {                         // geo bias table (log2-domain)
        int i = bx * 256 + t;
        if (i >= TBL) return;
        float d = (float)i * (6.0f / (float)(TBL - 1));
        float rbf[GH];
#pragma unroll
        for (int j = 0; j < GH; ++j) {
            float c = 0.4f * (float)j;
            float tt = d - c;
            rbf[j] = __expf(-tt * tt);
        }
        float hid[GH];
#pragma unroll
        for (int j = 0; j < GH; ++j) {
            float acc = bg1[j];
#pragma unroll
            for (int kk = 0; kk < GH; ++kk) acc += rbf[kk] * Wg1[j * GH + kk];
            hid[j] = fmaxf(acc, 0.0f);
        }
#pragma unroll
        for (int h = 0; h < NH; ++h) {
            float acc = bg2[h];
#pragma unroll
            for (int j = 0; j < GH; ++j) acc += hid[j] * Wg2[h * GH + j];
            tbl[i * NH + h] = acc * LOG2E;
        }
        return;
    }
    // last block: zero gbin
    for (int i = t; i < nbins; i += 256) gbin[i] = 0;
}

// ---------------- qkv (128x128 tile, 512 thr / 8 waves) + phase-1 bin scatter at FRONT ----------------
__global__ __launch_bounds__(512, 4) void qkv_kernel(
    const unsigned short* __restrict__ xh, const unsigned short* __restrict__ xl,
    const unsigned short* __restrict__ wh, const unsigned short* __restrict__ wl,
    const float* __restrict__ bq, const float* __restrict__ bk, const float* __restrict__ bv,
    float* __restrict__ q, unsigned short* __restrict__ kb, unsigned short* __restrict__ vb,
    const int* __restrict__ ei, const float* __restrict__ edist,
    int* __restrict__ gbin, int2* __restrict__ binbuf,
    int Nn, int E_, int nxb, int nb1, int nbins) {
    __shared__ unsigned short xh_s[128 * 40];
    __shared__ unsigned short xl_s[128 * 40];
    __shared__ unsigned short wh_s[128 * 40];
    __shared__ unsigned short wl_s[128 * 40];

    const int tid = threadIdx.x;
    int bx = blockIdx.x;

    if (bx < nb1) {
        // ---- phase 1: bin scatter (runs first -> overlaps GEMM blocks) ----
        int* hist = (int*)xh_s;              // reuse LDS
        const int e0 = bx * 4096;
        for (int b = tid; b < nbins; b += 512) hist[b] = 0;
        __syncthreads();
#pragma unroll
        for (int i = 0; i < 8; ++i) {
            int e = e0 + tid + i * 512;
            if (e < E_) atomicAdd(&hist[ei[e] >> 7], 1);
        }
        __syncthreads();
        for (int b = tid; b < nbins; b += 512) {
            int h = hist[b];
            int base = 0;
            if (h) base = atomicAdd(&gbin[b], h);   // ~nonzero-bins global atomics only
            hist[b] = base;
        }
        __syncthreads();
#pragma unroll
        for (int i = 0; i < 8; ++i) {
            int e = e0 + tid + i * 512;
            if (e < E_) {
                int row = ei[e];
                int bin = row >> 7;
                int r = atomicAdd(&hist[bin], 1);
                float u = edist[e] * ((float)(TBL - 1) / 6.0f);
                u = fminf(fmaxf(u, 0.0f), (float)(TBL - 1));
                if (r < BCAP)
                    binbuf[(size_t)bin * BCAP + r] =
                        make_int2((ei[E_ + e] & 0x1FFFF) | ((row & 127) << 17), __float_as_int(u));
            }
        }
        return;
    }
    bx -= nb1;

    const int wsel = bx / nxb;
    const int n0 = (bx - wsel * nxb) * 128;
    const unsigned short* W_h = wh + (size_t)wsel * (OUT_DIM * IN_DIM);
    const unsigned short* W_l = wl + (size_t)wsel * (OUT_DIM * IN_DIM);
    const float* bias = (wsel == 0) ? bq : (wsel == 1) ? bk : bv;
    const bool vpath = (wsel == 2);

    const int w = tid >> 6;          // 0..7
    const int lane = tid & 63;
    const int ml = lane & 15;
    const int quad = lane >> 4;
    const int rg = w & 3;            // rows rg*32 .. rg*32+31
    const int cg = w >> 2;           // cols cg*64 .. cg*64+63

    const int rows_valid = min(128, Nn - n0);

    floatx4 acc[2][4];
#pragma unroll
    for (int rr = 0; rr < 2; ++rr)
#pragma unroll
        for (int ct = 0; ct < 4; ++ct) acc[rr][ct] = (floatx4){0.f, 0.f, 0.f, 0.f};

    const short8 zero8 = {0, 0, 0, 0, 0, 0, 0, 0};

    for (int kc = 0; kc < IN_DIM; kc += 32) {
        {
            int r = tid >> 2, c = tid & 3;   // 512 threads -> 128 rows x 4 chunks
            size_t gx = (size_t)(n0 + r) * IN_DIM + kc + c * 8;
            size_t gw = (size_t)r * IN_DIM + kc + c * 8;
            short8 vh = zero8;
            if (r < rows_valid) vh = *(const short8*)(xh + gx);
            *(short8*)(xh_s + r * 40 + c * 8) = vh;
            *(short8*)(wh_s + r * 40 + c * 8) = *(const short8*)(W_h + gw);
            if (vpath) {
                short8 vl = zero8;
                if (r < rows_valid) vl = *(const short8*)(xl + gx);
                *(short8*)(xl_s + r * 40 + c * 8) = vl;
                *(short8*)(wl_s + r * 40 + c * 8) = *(const short8*)(W_l + gw);
            }
        }
        __syncthreads();

        short8 ah0 = *(const short8*)(xh_s + (rg * 32 + ml) * 40 + quad * 8);
        short8 ah1 = *(const short8*)(xh_s + (rg * 32 + 16 + ml) * 40 + quad * 8);
        if (!vpath) {
#pragma unroll
            for (int ct = 0; ct < 4; ++ct) {
                short8 bh = *(const short8*)(wh_s + (cg * 64 + ct * 16 + ml) * 40 + quad * 8);
                acc[0][ct] = __builtin_amdgcn_mfma_f32_16x16x32_bf16(ah0, bh, acc[0][ct], 0, 0, 0);
                acc[1][ct] = __builtin_amdgcn_mfma_f32_16x16x32_bf16(ah1, bh, acc[1][ct], 0, 0, 0);
            }
        } else {
            short8 al0 = *(const short8*)(xl_s + (rg * 32 + ml) * 40 + quad * 8);
            short8 al1 = *(const short8*)(xl_s + (rg * 32 + 16 + ml) * 40 + quad * 8);
#pragma unroll
            for (int ct = 0; ct < 4; ++ct) {
                short8 bh = *(const short8*)(wh_s + (cg * 64 + ct * 16 + ml) * 40 + quad * 8);
                short8 bl = *(const short8*)(wl_s + (cg * 64 + ct * 16 + ml) * 40 + quad * 8);
                acc[0][ct] = __builtin_amdgcn_mfma_f32_16x16x32_bf16(ah0, bh, acc[0][ct], 0, 0, 0);
                acc[0][ct] = __builtin_amdgcn_mfma_f32_16x16x32_bf16(al0, bh, acc[0][ct], 0, 0, 0);
                acc[0][ct] = __builtin_amdgcn_mfma_f32_16x16x32_bf16(ah0, bl, acc[0][ct], 0, 0, 0);
                acc[1][ct] = __builtin_amdgcn_mfma_f32_16x16x32_bf16(ah1, bh, acc[1][ct], 0, 0, 0);
                acc[1][ct] = __builtin_amdgcn_mfma_f32_16x16x32_bf16(al1, bh, acc[1][ct], 0, 0, 0);
                acc[1][ct] = __builtin_amdgcn_mfma_f32_16x16x32_bf16(ah1, bl, acc[1][ct], 0, 0, 0);
            }
        }
        __syncthreads();
    }

    if (wsel == 0) {
#pragma unroll
        for (int rr = 0; rr < 2; ++rr)
#pragma unroll
            for (int ct = 0; ct < 4; ++ct) {
                int col = cg * 64 + ct * 16 + ml;
                float bj = bias[col];
#pragma unroll
                for (int r = 0; r < 4; ++r) {
                    int grow = n0 + rg * 32 + rr * 16 + quad * 4 + r;
                    if (grow < Nn) q[(size_t)grow * 128 + col] = acc[rr][ct][r] + bj;
                }
            }
    } else {
        unsigned short* ob = (wsel == 1) ? kb : vb;
#pragma unroll
        for (int rr = 0; rr < 2; ++rr)
#pragma unroll
            for (int ct = 0; ct < 4; ++ct) {
                int col = cg * 64 + ct * 16 + ml;
                float bj = bias[col];
#pragma unroll
                for (int r = 0; r < 4; ++r) {
                    int grow = n0 + rg * 32 + rr * 16 + quad * 4 + r;
                    if (grow < Nn) ob[(size_t)grow * 128 + col] = f2bf(acc[rr][ct][r] + bj);
                }
            }
    }
}

// ---------------- phase 2: bin -> compact CSR-per-bin (LDS rank+prefix, coalesced out) ----------------
__global__ __launch_bounds__(256) void bin2bucket_kernel(
    const int2* __restrict__ binbuf, const int* __restrict__ gbin,
    int2* __restrict__ bucket, int* __restrict__ rowstart, int* __restrict__ cnt, int Nn) {
    __shared__ int rcnt[128];
    __shared__ int pref[128];
    __shared__ int2 ebuf[BCAP];
    const int bin = blockIdx.x;
    const int t = threadIdx.x;
    if (t < 128) rcnt[t] = 0;
    __syncthreads();
    int nb = gbin[bin];
    if (nb > BCAP) nb = BCAP;
    const int row0 = bin << 7;

    int px[10], py[10], rk[10];          // fully unrolled -> stays in VGPRs
#pragma unroll
    for (int j = 0; j < 10; ++j) {
        int i = t + j * 256;
        rk[j] = -1;
        if (i < nb) {
            int2 p = binbuf[(size_t)bin * BCAP + i];
            int rowrel = (p.x >> 17) & 127;
            int r = atomicAdd(&rcnt[rowrel], 1);
            if (r < RCAP) { px[j] = p.x & 0x1FFFF; py[j] = p.y; rk[j] = r | (rowrel << 16); }
        }
    }
    __syncthreads();
    int myclamp = 0;
    if (t < 128) { myclamp = min(rcnt[t], RCAP); pref[t] = myclamp; }
    __syncthreads();
    for (int off = 1; off < 128; off <<= 1) {
        int v = 0;
        if (t < 128 && t >= off) v = pref[t - off];
        __syncthreads();
        if (t < 128) pref[t] += v;
        __syncthreads();
    }
    // pref inclusive; exclusive start for row r = pref[r] - clamp[r]
#pragma unroll
    for (int j = 0; j < 10; ++j) {
        if (rk[j] >= 0) {
            int rowrel = rk[j] >> 16;
            int r = rk[j] & 0xFFFF;
            int pos = pref[rowrel] - min(rcnt[rowrel], RCAP) + r;
            ebuf[pos] = make_int2(px[j], py[j]);
        }
    }
    __syncthreads();
    int total = pref[127];
    const int obase = bin * BCAP;
    for (int i = t; i < total; i += 256) bucket[obase + i] = ebuf[i];   // coalesced
    if (t < 128 && row0 + t < Nn) {
        rowstart[row0 + t] = obase + pref[t] - myclamp;
        cnt[row0 + t] = myclamp;
    }
}

// ---------------- fused flash-style edge+node pass (CSR, prefetch, f32 output) ----------------
__global__ __launch_bounds__(256) void fused_node_kernel(
    const float* __restrict__ q, const unsigned short* __restrict__ kb,
    const unsigned short* __restrict__ vb, const int2* __restrict__ bucket,
    const float* __restrict__ tbl, const int* __restrict__ rowstart, const int* __restrict__ cnt,
    float* __restrict__ o, int Nn) {
    int lane = threadIdx.x & 63;
    int n = blockIdx.x * 4 + (threadIdx.x >> 6);
    if (n >= Nn) return;
    int g = lane >> 3;       // edge subgroup
    int h = lane & 7;        // head
    int start = rowstart[n];
    int end = start + cnt[n];

    float qf[16];
    {
        const float4* qp = (const float4*)(q + (size_t)n * 128 + h * 16);
#pragma unroll
        for (int j = 0; j < 4; ++j) {
            float4 t = qp[j];
            qf[j * 4 + 0] = t.x; qf[j * 4 + 1] = t.y;
            qf[j * 4 + 2] = t.z; qf[j * 4 + 3] = t.w;
        }
    }

    float l = 0.0f;
    float acc[16];
#pragma unroll
    for (int j = 0; j < 16; ++j) acc[j] = 0.0f;

    int2 np;
    if (start < end) np = bucket[min(start + g, end - 1)];

#pragma unroll 2
    for (int base = start; base < end; base += 8) {
        bool valid = (base + g < end);
        int2 cur = np;
        int nxt = base + 8;
        if (nxt < end) np = bucket[min(nxt + g, end - 1)];   // prefetch next tile

        int col = cur.x;
        float u = __int_as_float(cur.y);

        const uint4* kp = (const uint4*)(kb + (size_t)col * 128 + h * 16);
        uint4 k0 = kp[0], k1 = kp[1];
        const uint4* vp = (const uint4*)(vb + (size_t)col * 128 + h * 16);
        uint4 v0 = vp[0], v1 = vp[1];

        unsigned kk[8] = {k0.x, k0.y, k0.z, k0.w, k1.x, k1.y, k1.z, k1.w};
        float d = 0.0f;
#pragma unroll
        for (int j = 0; j < 8; ++j) {
            d = fmaf(bflo(kk[j]), qf[2 * j], d);
            d = fmaf(bfhi(kk[j]), qf[2 * j + 1], d);
        }

        int i0 = min((int)u, TBL - 2);
        float fr = u - (float)i0;
        float t0 = tbl[i0 * NH + h];
        float t1 = tbl[i0 * NH + NH + h];
        float logit2 = fmaf(d, 0.25f * LOG2E, fmaf(fr, t1 - t0, t0));
        logit2 = fminf(logit2, 80.0f);
        if (!valid) logit2 = -1e30f;
        float p = __builtin_amdgcn_exp2f(logit2);

        l += p;
        unsigned vv[8] = {v0.x, v0.y, v0.z, v0.w, v1.x, v1.y, v1.z, v1.w};
#pragma unroll
        for (int j = 0; j < 8; ++j) {
            acc[2 * j]     = fmaf(p, bflo(vv[j]), acc[2 * j]);
            acc[2 * j + 1] = fmaf(p, bfhi(vv[j]), acc[2 * j + 1]);
        }
    }

#pragma unroll
    for (int off = 8; off < 64; off <<= 1) {
        l += __shfl_xor(l, off);
#pragma unroll
        for (int j = 0; j < 16; ++j) acc[j] += __shfl_xor(acc[j], off);
    }

    if (g == 0) {
        float inv = 1.0f / (l + 1e-12f);
        float4* op = (float4*)(o + (size_t)n * 128 + h * 16);
#pragma unroll
        for (int j = 0; j < 4; ++j) {
            float4 t;
            t.x = acc[j * 4 + 0] * inv; t.y = acc[j * 4 + 1] * inv;
            t.z = acc[j * 4 + 2] * inv; t.w = acc[j * 4 + 3] * inv;
            op[j] = t;
        }
    }
}

// ---------------- out GEMM (128-row tile, 512 thr / 8 waves), split-bf16 MFMA K=128 ----------------
__global__ __launch_bounds__(512, 4) void out_gemm_mfma_kernel(
    const float* __restrict__ o,
    const unsigned short* __restrict__ wo_h, const unsigned short* __restrict__ wo_l,
    const float* __restrict__ bo, float* __restrict__ out, int Nn) {
    const int n0 = blockIdx.x * 128;

    __shared__ unsigned short xh_s[128 * 40];
    __shared__ unsigned short xl_s[128 * 40];
    __shared__ unsigned short wh_s[128 * 40];
    __shared__ unsigned short wl_s[128 * 40];

    const int tid = threadIdx.x;
    const int w = tid >> 6;
    const int lane = tid & 63;
    const int ml = lane & 15;
    const int quad = lane >> 4;
    const int rg = w & 3;
    const int cg = w >> 2;

    const int rows_valid = min(128, Nn - n0);

    floatx4 acc[2][4];
#pragma unroll
    for (int rr = 0; rr < 2; ++rr)
#pragma unroll
        for (int ct = 0; ct < 4; ++ct) acc[rr][ct] = (floatx4){0.f, 0.f, 0.f, 0.f};

    for (int kc = 0; kc < OUT_DIM; kc += 32) {
        {
            int r = tid >> 2, c = tid & 3;
            unsigned short hv[8], lv[8];
            if (r < rows_valid) {
                const float* src = o + (size_t)(n0 + r) * OUT_DIM + kc + c * 8;
#pragma unroll
                for (int j = 0; j < 8; ++j) split1(src[j], hv[j], lv[j]);
            } else {
#pragma unroll
                for (int j = 0; j < 8; ++j) { hv[j] = 0; lv[j] = 0; }
            }
            *(short8*)(xh_s + r * 40 + c * 8) = *(short8*)hv;
            *(short8*)(xl_s + r * 40 + c * 8) = *(short8*)lv;
            size_t gg = (size_t)r * OUT_DIM + kc + c * 8;
            *(short8*)(wh_s + r * 40 + c * 8) = *(const short8*)(wo_h + gg);
            *(short8*)(wl_s + r * 40 + c * 8) = *(const short8*)(wo_l + gg);
        }
        __syncthreads();

        short8 ah0 = *(const short8*)(xh_s + (rg * 32 + ml) * 40 + quad * 8);
        short8 ah1 = *(const short8*)(xh_s + (rg * 32 + 16 + ml) * 40 + quad * 8);
        short8 al0 = *(const short8*)(xl_s + (rg * 32 + ml) * 40 + quad * 8);
        short8 al1 = *(const short8*)(xl_s + (rg * 32 + 16 + ml) * 40 + quad * 8);
#pragma unroll
        for (int ct = 0; ct < 4; ++ct) {
            short8 bh = *(const short8*)(wh_s + (cg * 64 + ct * 16 + ml) * 40 + quad * 8);
            short8 bl = *(const short8*)(wl_s + (cg * 64 + ct * 16 + ml) * 40 + quad * 8);
            acc[0][ct] = __builtin_amdgcn_mfma_f32_16x16x32_bf16(ah0, bh, acc[0][ct], 0, 0, 0);
            acc[0][ct] = __builtin_amdgcn_mfma_f32_16x16x32_bf16(al0, bh, acc[0][ct], 0, 0, 0);
            acc[0][ct] = __builtin_amdgcn_mfma_f32_16x16x32_bf16(ah0, bl, acc[0][ct], 0, 0, 0);
            acc[1][ct] = __builtin_amdgcn_mfma_f32_16x16x32_bf16(ah1, bh, acc[1][ct], 0, 0, 0);
            acc[1][ct] = __builtin_amdgcn_mfma_f32_16x16x32_bf16(al1, bh, acc[1][ct], 0, 0, 0);
            acc[1][ct] = __builtin_amdgcn_mfma_f32_16x16x32_bf16(ah1, bl, acc[1][ct], 0, 0, 0);
        }
        __syncthreads();
    }

#pragma unroll
    for (int rr = 0; rr < 2; ++rr)
#pragma unroll
        for (int ct = 0; ct < 4; ++ct) {
            int col = cg * 64 + ct * 16 + ml;
            float bj = bo[col];
#pragma unroll
            for (int r = 0; r < 4; ++r) {
                int grow = n0 + rg * 32 + rr * 16 + quad * 4 + r;
                if (grow < Nn) out[(size_t)grow * 128 + col] = acc[rr][ct][r] + bj;
            }
        }
}

extern "C" void kernel_launch(void* const* d_in, const int* in_sizes, int n_in,
                              void* d_out, int out_size, void* d_ws, size_t ws_size,
                              hipStream_t stream) {
    const float* x   = (const float*)d_in[0];
    const int* ei    = (const int*)d_in[1];
    const float* edist = (const float*)d_in[2];
    const float* Wq = (const float*)d_in[3];  const float* bq = (const float*)d_in[4];
    const float* Wk = (const float*)d_in[5];  const float* bk = (const float*)d_in[6];
    const float* Wv = (const float*)d_in[7];  const float* bv = (const float*)d_in[8];
    const float* Wo = (const float*)d_in[9];  const float* bo = (const float*)d_in[10];
    const float* Wg1 = (const float*)d_in[11]; const float* bg1 = (const float*)d_in[12];
    const float* Wg2 = (const float*)d_in[13]; const float* bg2 = (const float*)d_in[14];
    const int Nn = in_sizes[0] / IN_DIM;
    const int Ee = in_sizes[2];
    float* out = (float*)d_out;

    char* ws = (char*)d_ws;
    size_t off = 0;
    auto alloc = [&](size_t bytes) -> char* {
        char* p = ws + off;
        off += (bytes + 255) & ~(size_t)255;
        return p;
    };
    float* q  = (float*)alloc((size_t)Nn * 128 * 4);
    unsigned short* kbuf = (unsigned short*)alloc((size_t)Nn * 128 * 2);
    unsigned short* vbuf = (unsigned short*)alloc((size_t)Nn * 128 * 2);
    char* xlblock = alloc((size_t)Nn * IN_DIM * 2);
    float* o = (float*)alloc((size_t)Nn * 128 * 4);       // f32 attention output; binbuf aliases it
    float* geot = (float*)alloc((size_t)TBL * 8 * 4);
    int* cnt = (int*)alloc((size_t)Nn * 4);
    int* rowstart = (int*)alloc((size_t)Nn * 4);
    int nbins = (Nn + 127) >> 7;
    int* gbin = (int*)alloc((size_t)nbins * 4);
    unsigned short* wh_all = (unsigned short*)alloc((size_t)3 * OUT_DIM * IN_DIM * 2);
    unsigned short* wl_all = (unsigned short*)alloc((size_t)3 * OUT_DIM * IN_DIM * 2);
    unsigned short* wo_h = (unsigned short*)alloc((size_t)OUT_DIM * OUT_DIM * 2);
    unsigned short* wo_l = (unsigned short*)alloc((size_t)OUT_DIM * OUT_DIM * 2);
    int2* bucket = (int2*)alloc((size_t)nbins * BCAP * 8);   // 8.0 MB compact CSR-per-bin

    // binbuf aliases o: nbins*BCAP*8 = 8.0 MB <= Nn*512 B = 25.6 MB.
    // Lifetime: binbuf written in qkv dispatch (phase1), read in bin2bucket,
    // dead before fused_node writes o. No overlap.
    int2* binbuf = (int2*)o;

    unsigned short* xh = (unsigned short*)d_out;       // rewritten by final GEMM
    unsigned short* xl = (unsigned short*)xlblock;

    // --- dispatch 1: prep_all ---
    int n4x = Nn * IN_DIM / 4;
    int nsplit = (n4x + 255) / 256;
    int nwm = ((OUT_DIM * IN_DIM / 4) + 255) / 256;
    int nwo = ((OUT_DIM * OUT_DIM / 4) + 255) / 256;
    int ngeo = (TBL + 255) / 256;
    int gprep = nsplit + 3 * nwm + nwo + ngeo + 1;     // +1 block zeroes gbin
    prep_all_kernel<<<gprep, 256, 0, stream>>>(
        x, Wq, Wk, Wv, Wo, xh, xl, wh_all, wl_all, wo_h, wo_l,
        Wg1, bg1, Wg2, bg2, geot, gbin, n4x, nbins, nsplit, nwm, nwo, ngeo);

    // --- dispatch 2: [phase1 bin-scatter blocks first] + qkv GEMM blocks (512 thr) ---
    int nxb = (Nn + 127) / 128;
    int nb1 = (Ee + 4095) / 4096;
    qkv_kernel<<<nb1 + 3 * nxb, 512, 0, stream>>>(
        xh, xl, wh_all, wl_all, bq, bk, bv, q, kbuf, vbuf,
        ei, edist, gbin, binbuf, Nn, Ee, nxb, nb1, nbins);

    // --- dispatch 3: phase2 bin -> compact CSR buckets (coalesced writes) ---
    bin2bucket_kernel<<<nbins, 256, 0, stream>>>(binbuf, gbin, bucket, rowstart, cnt, Nn);

    // --- dispatch 4: fused edge+node ---
    fused_node_kernel<<<(Nn + 3) / 4, 256, 0, stream>>>(q, kbuf, vbuf, bucket, geot, rowstart, cnt, o, Nn);

    // --- dispatch 5: out GEMM (128-row tiles, 512 thr) ---
    out_gemm_mfma_kernel<<<(Nn + 127) / 128, 512, 0, stream>>>(o, wo_h, wo_l, bo, out, Nn);
}

// Round 5
// 267.716 us; speedup vs baseline: 1.2527x; 1.0112x over previous
//
#include <hip/hip_runtime.h>
#include <math.h>

#define IN_DIM 256
#define OUT_DIM 128
#define NH 8
#define HD 16
#define GH 16
#define TBL 1024
#define LOG2E 1.44269504f
// R16: fused_node rewritten as persistent grid-stride waves + 2-level pipeline.
// R15 post-mortem: fused_node 63us, VALUBusy 45%, occupancy 54% -> half VALU,
// half unhidden meta->bucket->K/V latency (12500 short blocks, 1-tile lookahead).
//  - 2048 persistent blocks (8/CU); each wave strides nodes, prefetches next
//    node's meta (int2{start,cnt}) during current compute.
//  - first TWO 8-edge tiles loaded up-front (2 bucket + 8 K/V loads in flight;
//    deg<=16 = 84% of nodes need no serial loop). Tail loop only for deg>16.
//  - bin2bucket now emits meta[] (packed rowstart+cnt, one 8B load per node).
#define RCAP 64
#define BCAP 2560   // bin capacity: Poisson(2048) per 128-row bin, +11 sigma

typedef __attribute__((ext_vector_type(8))) short short8;
typedef __attribute__((ext_vector_type(4))) float floatx4;

// ---------------- bf16 helpers (RNE) ----------------
__device__ __forceinline__ unsigned short f2bf(float f) {
    union { float f; unsigned u; } v; v.f = f;
    unsigned r = v.u + 0x7fffu + ((v.u >> 16) & 1u);
    return (unsigned short)(r >> 16);
}
__device__ __forceinline__ float bf2f(unsigned short h) {
    union { unsigned u; float f; } v; v.u = ((unsigned)h) << 16;
    return v.f;
}
__device__ __forceinline__ void split1(float f, unsigned short& h, unsigned short& l) {
    h = f2bf(f);
    l = f2bf(f - bf2f(h));
}
__device__ __forceinline__ float bflo(unsigned u) { return __uint_as_float(u << 16); }
__device__ __forceinline__ float bfhi(unsigned u) { return __uint_as_float(u & 0xffff0000u); }

// ---------------- prep_all: split x, split Wq/Wk/Wv/Wo, geo table, zero gbin ----------------
__global__ __launch_bounds__(256) void prep_all_kernel(
    const float* __restrict__ x, const float* __restrict__ Wq, const float* __restrict__ Wk,
    const float* __restrict__ Wv, const float* __restrict__ Wo,
    unsigned short* __restrict__ xh, unsigned short* __restrict__ xl,
    unsigned short* __restrict__ wh, unsigned short* __restrict__ wl,
    unsigned short* __restrict__ wo_h, unsigned short* __restrict__ wo_l,
    const float* __restrict__ Wg1, const float* __restrict__ bg1,
    const float* __restrict__ Wg2, const float* __restrict__ bg2,
    float* __restrict__ tbl, int* __restrict__ gbin,
    int n4x, int nbins, int nsplit, int nwm, int nwo, int ngeo) {
    int bx = blockIdx.x;
    int t = threadIdx.x;

    if (bx < nsplit) {                       // split x
        int i = bx * 256 + t;
        if (i >= n4x) return;
        float4 f = ((const float4*)x)[i];
        ushort4 h, l;
        split1(f.x, h.x, l.x); split1(f.y, h.y, l.y);
        split1(f.z, h.z, l.z); split1(f.w, h.w, l.w);
        ((ushort4*)xh)[i] = h;
        ((ushort4*)xl)[i] = l;
        return;
    }
    bx -= nsplit;
    if (bx < 3 * nwm) {                      // split Wq/Wk/Wv
        int m = bx / nwm;
        int i = (bx - m * nwm) * 256 + t;
        if (i >= (OUT_DIM * IN_DIM) / 4) return;
        const float* W = (m == 0) ? Wq : (m == 1) ? Wk : Wv;
        float4 f = ((const float4*)W)[i];
        ushort4 h, l;
        split1(f.x, h.x, l.x); split1(f.y, h.y, l.y);
        split1(f.z, h.z, l.z); split1(f.w, h.w, l.w);
        size_t base = (size_t)m * (OUT_DIM * IN_DIM) / 4;
        ((ushort4*)wh)[base + i] = h;
        ((ushort4*)wl)[base + i] = l;
        return;
    }
    bx -= 3 * nwm;
    if (bx < nwo) {                          // split Wo
        int i = bx * 256 + t;
        if (i >= (OUT_DIM * OUT_DIM) / 4) return;
        float4 f = ((const float4*)Wo)[i];
        ushort4 h, l;
        split1(f.x, h.x, l.x); split1(f.y, h.y, l.y);
        split1(f.z, h.z, l.z); split1(f.w, h.w, l.w);
        ((ushort4*)wo_h)[i] = h;
        ((ushort4*)wo_l)[i] = l;
        return;
    }
    bx -= nwo;
    if (bx < ngeo) {                         // geo bias table (log2-domain)
        int i = bx * 256 + t;
        if (i >= TBL) return;
        float d = (float)i * (6.0f / (float)(TBL - 1));
        float rbf[GH];
#pragma unroll
        for (int j = 0; j < GH; ++j) {
            float c = 0.4f * (float)j;
            float tt = d - c;
            rbf[j] = __expf(-tt * tt);
        }
        float hid[GH];
#pragma unroll
        for (int j = 0; j < GH; ++j) {
            float acc = bg1[j];
#pragma unroll
            for (int kk = 0; kk < GH; ++kk) acc += rbf[kk] * Wg1[j * GH + kk];
            hid[j] = fmaxf(acc, 0.0f);
        }
#pragma unroll
        for (int h = 0; h < NH; ++h) {
            float acc = bg2[h];
#pragma unroll
            for (int j = 0; j < GH; ++j) acc += hid[j] * Wg2[h * GH + j];
            tbl[i * NH + h] = acc * LOG2E;
        }
        return;
    }
    // last block: zero gbin
    for (int i = t; i < nbins; i += 256) gbin[i] = 0;
}

// ---------------- qkv (128x128 tile, 512 thr / 8 waves) + phase-1 bin scatter at FRONT ----------------
__global__ __launch_bounds__(512, 4) void qkv_kernel(
    const unsigned short* __restrict__ xh, const unsigned short* __restrict__ xl,
    const unsigned short* __restrict__ wh, const unsigned short* __restrict__ wl,
    const float* __restrict__ bq, const float* __restrict__ bk, const float* __restrict__ bv,
    float* __restrict__ q, unsigned short* __restrict__ kb, unsigned short* __restrict__ vb,
    const int* __restrict__ ei, const float* __restrict__ edist,
    int* __restrict__ gbin, int2* __restrict__ binbuf,
    int Nn, int E_, int nxb, int nb1, int nbins) {
    __shared__ unsigned short xh_s[128 * 40];
    __shared__ unsigned short xl_s[128 * 40];
    __shared__ unsigned short wh_s[128 * 40];
    __shared__ unsigned short wl_s[128 * 40];

    const int tid = threadIdx.x;
    int bx = blockIdx.x;

    if (bx < nb1) {
        // ---- phase 1: bin scatter (runs first -> overlaps GEMM blocks) ----
        int* hist = (int*)xh_s;              // reuse LDS
        const int e0 = bx * 4096;
        for (int b = tid; b < nbins; b += 512) hist[b] = 0;
        __syncthreads();
#pragma unroll
        for (int i = 0; i < 8; ++i) {
            int e = e0 + tid + i * 512;
            if (e < E_) atomicAdd(&hist[ei[e] >> 7], 1);
        }
        __syncthreads();
        for (int b = tid; b < nbins; b += 512) {
            int h = hist[b];
            int base = 0;
            if (h) base = atomicAdd(&gbin[b], h);   // ~nonzero-bins global atomics only
            hist[b] = base;
        }
        __syncthreads();
#pragma unroll
        for (int i = 0; i < 8; ++i) {
            int e = e0 + tid + i * 512;
            if (e < E_) {
                int row = ei[e];
                int bin = row >> 7;
                int r = atomicAdd(&hist[bin], 1);
                float u = edist[e] * ((float)(TBL - 1) / 6.0f);
                u = fminf(fmaxf(u, 0.0f), (float)(TBL - 1));
                if (r < BCAP)
                    binbuf[(size_t)bin * BCAP + r] =
                        make_int2((ei[E_ + e] & 0x1FFFF) | ((row & 127) << 17), __float_as_int(u));
            }
        }
        return;
    }
    bx -= nb1;

    const int wsel = bx / nxb;
    const int n0 = (bx - wsel * nxb) * 128;
    const unsigned short* W_h = wh + (size_t)wsel * (OUT_DIM * IN_DIM);
    const unsigned short* W_l = wl + (size_t)wsel * (OUT_DIM * IN_DIM);
    const float* bias = (wsel == 0) ? bq : (wsel == 1) ? bk : bv;
    const bool vpath = (wsel == 2);

    const int w = tid >> 6;          // 0..7
    const int lane = tid & 63;
    const int ml = lane & 15;
    const int quad = lane >> 4;
    const int rg = w & 3;            // rows rg*32 .. rg*32+31
    const int cg = w >> 2;           // cols cg*64 .. cg*64+63

    const int rows_valid = min(128, Nn - n0);

    floatx4 acc[2][4];
#pragma unroll
    for (int rr = 0; rr < 2; ++rr)
#pragma unroll
        for (int ct = 0; ct < 4; ++ct) acc[rr][ct] = (floatx4){0.f, 0.f, 0.f, 0.f};

    const short8 zero8 = {0, 0, 0, 0, 0, 0, 0, 0};

    for (int kc = 0; kc < IN_DIM; kc += 32) {
        {
            int r = tid >> 2, c = tid & 3;   // 512 threads -> 128 rows x 4 chunks
            size_t gx = (size_t)(n0 + r) * IN_DIM + kc + c * 8;
            size_t gw = (size_t)r * IN_DIM + kc + c * 8;
            short8 vh = zero8;
            if (r < rows_valid) vh = *(const short8*)(xh + gx);
            *(short8*)(xh_s + r * 40 + c * 8) = vh;
            *(short8*)(wh_s + r * 40 + c * 8) = *(const short8*)(W_h + gw);
            if (vpath) {
                short8 vl = zero8;
                if (r < rows_valid) vl = *(const short8*)(xl + gx);
                *(short8*)(xl_s + r * 40 + c * 8) = vl;
                *(short8*)(wl_s + r * 40 + c * 8) = *(const short8*)(W_l + gw);
            }
        }
        __syncthreads();

        short8 ah0 = *(const short8*)(xh_s + (rg * 32 + ml) * 40 + quad * 8);
        short8 ah1 = *(const short8*)(xh_s + (rg * 32 + 16 + ml) * 40 + quad * 8);
        if (!vpath) {
#pragma unroll
            for (int ct = 0; ct < 4; ++ct) {
                short8 bh = *(const short8*)(wh_s + (cg * 64 + ct * 16 + ml) * 40 + quad * 8);
                acc[0][ct] = __builtin_amdgcn_mfma_f32_16x16x32_bf16(ah0, bh, acc[0][ct], 0, 0, 0);
                acc[1][ct] = __builtin_amdgcn_mfma_f32_16x16x32_bf16(ah1, bh, acc[1][ct], 0, 0, 0);
            }
        } else {
            short8 al0 = *(const short8*)(xl_s + (rg * 32 + ml) * 40 + quad * 8);
            short8 al1 = *(const short8*)(xl_s + (rg * 32 + 16 + ml) * 40 + quad * 8);
#pragma unroll
            for (int ct = 0; ct < 4; ++ct) {
                short8 bh = *(const short8*)(wh_s + (cg * 64 + ct * 16 + ml) * 40 + quad * 8);
                short8 bl = *(const short8*)(wl_s + (cg * 64 + ct * 16 + ml) * 40 + quad * 8);
                acc[0][ct] = __builtin_amdgcn_mfma_f32_16x16x32_bf16(ah0, bh, acc[0][ct], 0, 0, 0);
                acc[0][ct] = __builtin_amdgcn_mfma_f32_16x16x32_bf16(al0, bh, acc[0][ct], 0, 0, 0);
                acc[0][ct] = __builtin_amdgcn_mfma_f32_16x16x32_bf16(ah0, bl, acc[0][ct], 0, 0, 0);
                acc[1][ct] = __builtin_amdgcn_mfma_f32_16x16x32_bf16(ah1, bh, acc[1][ct], 0, 0, 0);
                acc[1][ct] = __builtin_amdgcn_mfma_f32_16x16x32_bf16(al1, bh, acc[1][ct], 0, 0, 0);
                acc[1][ct] = __builtin_amdgcn_mfma_f32_16x16x32_bf16(ah1, bl, acc[1][ct], 0, 0, 0);
            }
        }
        __syncthreads();
    }

    if (wsel == 0) {
#pragma unroll
        for (int rr = 0; rr < 2; ++rr)
#pragma unroll
            for (int ct = 0; ct < 4; ++ct) {
                int col = cg * 64 + ct * 16 + ml;
                float bj = bias[col];
#pragma unroll
                for (int r = 0; r < 4; ++r) {
                    int grow = n0 + rg * 32 + rr * 16 + quad * 4 + r;
                    if (grow < Nn) q[(size_t)grow * 128 + col] = acc[rr][ct][r] + bj;
                }
            }
    } else {
        unsigned short* ob = (wsel == 1) ? kb : vb;
#pragma unroll
        for (int rr = 0; rr < 2; ++rr)
#pragma unroll
            for (int ct = 0; ct < 4; ++ct) {
                int col = cg * 64 + ct * 16 + ml;
                float bj = bias[col];
#pragma unroll
                for (int r = 0; r < 4; ++r) {
                    int grow = n0 + rg * 32 + rr * 16 + quad * 4 + r;
                    if (grow < Nn) ob[(size_t)grow * 128 + col] = f2bf(acc[rr][ct][r] + bj);
                }
            }
    }
}

// ---------------- phase 2: bin -> compact CSR-per-bin (LDS rank+prefix, coalesced out) ----------------
__global__ __launch_bounds__(256) void bin2bucket_kernel(
    const int2* __restrict__ binbuf, const int* __restrict__ gbin,
    int2* __restrict__ bucket, int2* __restrict__ meta, int Nn) {
    __shared__ int rcnt[128];
    __shared__ int pref[128];
    __shared__ int2 ebuf[BCAP];
    const int bin = blockIdx.x;
    const int t = threadIdx.x;
    if (t < 128) rcnt[t] = 0;
    __syncthreads();
    int nb = gbin[bin];
    if (nb > BCAP) nb = BCAP;
    const int row0 = bin << 7;

    int px[10], py[10], rk[10];          // fully unrolled -> stays in VGPRs
#pragma unroll
    for (int j = 0; j < 10; ++j) {
        int i = t + j * 256;
        rk[j] = -1;
        if (i < nb) {
            int2 p = binbuf[(size_t)bin * BCAP + i];
            int rowrel = (p.x >> 17) & 127;
            int r = atomicAdd(&rcnt[rowrel], 1);
            if (r < RCAP) { px[j] = p.x & 0x1FFFF; py[j] = p.y; rk[j] = r | (rowrel << 16); }
        }
    }
    __syncthreads();
    int myclamp = 0;
    if (t < 128) { myclamp = min(rcnt[t], RCAP); pref[t] = myclamp; }
    __syncthreads();
    for (int off = 1; off < 128; off <<= 1) {
        int v = 0;
        if (t < 128 && t >= off) v = pref[t - off];
        __syncthreads();
        if (t < 128) pref[t] += v;
        __syncthreads();
    }
    // pref inclusive; exclusive start for row r = pref[r] - clamp[r]
#pragma unroll
    for (int j = 0; j < 10; ++j) {
        if (rk[j] >= 0) {
            int rowrel = rk[j] >> 16;
            int r = rk[j] & 0xFFFF;
            int pos = pref[rowrel] - min(rcnt[rowrel], RCAP) + r;
            ebuf[pos] = make_int2(px[j], py[j]);
        }
    }
    __syncthreads();
    int total = pref[127];
    const int obase = bin * BCAP;
    for (int i = t; i < total; i += 256) bucket[obase + i] = ebuf[i];   // coalesced
    if (t < 128 && row0 + t < Nn)
        meta[row0 + t] = make_int2(obase + pref[t] - myclamp, myclamp);
}

// ---------------- fused flash-style edge+node pass: persistent waves, 2-level pipeline ----------------
__global__ __launch_bounds__(256) void fused_node_kernel(
    const float* __restrict__ q, const unsigned short* __restrict__ kb,
    const unsigned short* __restrict__ vb, const int2* __restrict__ bucket,
    const float* __restrict__ tbl, const int2* __restrict__ meta,
    float* __restrict__ o, int Nn, int nwav) {
    const int lane = threadIdx.x & 63;
    const int g = lane >> 3;     // edge subgroup (8 edges/tile)
    const int h = lane & 7;      // head
    int wid = blockIdx.x * (blockDim.x >> 6) + (threadIdx.x >> 6);
    if (wid >= Nn) return;

    int2 mnext = meta[wid];
    for (int n = wid; n < Nn; n += nwav) {
        const int2 m = mnext;
        const int n2 = n + nwav;
        if (n2 < Nn) mnext = meta[n2];       // prefetch next node's meta under this node's compute

        const int start = m.x;
        const int c = m.y;
        const int end = start + c;

        float qf[16];
        {
            const float4* qp = (const float4*)(q + (size_t)n * 128 + h * 16);
#pragma unroll
            for (int j = 0; j < 4; ++j) {
                float4 t = qp[j];
                qf[j * 4 + 0] = t.x; qf[j * 4 + 1] = t.y;
                qf[j * 4 + 2] = t.z; qf[j * 4 + 3] = t.w;
            }
        }

        float l = 0.0f;
        float acc[16];
#pragma unroll
        for (int j = 0; j < 16; ++j) acc[j] = 0.0f;

        auto edge_math = [&](const uint4& k0, const uint4& k1, const uint4& v0, const uint4& v1,
                             float u, bool valid) {
            unsigned kk[8] = {k0.x, k0.y, k0.z, k0.w, k1.x, k1.y, k1.z, k1.w};
            float d = 0.0f;
#pragma unroll
            for (int j = 0; j < 8; ++j) {
                d = fmaf(bflo(kk[j]), qf[2 * j], d);
                d = fmaf(bfhi(kk[j]), qf[2 * j + 1], d);
            }
            int i0 = min((int)u, TBL - 2);
            float fr = u - (float)i0;
            float t0 = tbl[i0 * NH + h];
            float t1 = tbl[i0 * NH + NH + h];
            float logit2 = fmaf(d, 0.25f * LOG2E, fmaf(fr, t1 - t0, t0));
            logit2 = fminf(logit2, 80.0f);
            if (!valid) logit2 = -1e30f;
            float p = __builtin_amdgcn_exp2f(logit2);
            l += p;
            unsigned vv[8] = {v0.x, v0.y, v0.z, v0.w, v1.x, v1.y, v1.z, v1.w};
#pragma unroll
            for (int j = 0; j < 8; ++j) {
                acc[2 * j]     = fmaf(p, bflo(vv[j]), acc[2 * j]);
                acc[2 * j + 1] = fmaf(p, bfhi(vv[j]), acc[2 * j + 1]);
            }
        };

        if (c > 0) {
            // tiles 0+1 up-front: 2 bucket + up to 8 K/V loads independent & in flight
            int2 npA = bucket[min(start + g, end - 1)];
            const bool vAv = (start + g < end);
            const bool doB = (end > start + 8);
            int2 npB = npA;
            bool vBv = false;
            if (doB) {
                npB = bucket[min(start + 8 + g, end - 1)];
                vBv = (start + 8 + g < end);
            }
            const uint4* kpA = (const uint4*)(kb + (size_t)npA.x * 128 + h * 16);
            const uint4* vpA = (const uint4*)(vb + (size_t)npA.x * 128 + h * 16);
            uint4 kA0 = kpA[0], kA1 = kpA[1], vA0 = vpA[0], vA1 = vpA[1];
            uint4 kB0, kB1, vB0, vB1;
            if (doB) {
                const uint4* kpB = (const uint4*)(kb + (size_t)npB.x * 128 + h * 16);
                const uint4* vpB = (const uint4*)(vb + (size_t)npB.x * 128 + h * 16);
                kB0 = kpB[0]; kB1 = kpB[1]; vB0 = vpB[0]; vB1 = vpB[1];
            }
            edge_math(kA0, kA1, vA0, vA1, __int_as_float(npA.y), vAv);
            if (doB) edge_math(kB0, kB1, vB0, vB1, __int_as_float(npB.y), vBv);
            // rare tail: degree > 16
            for (int base = start + 16; base < end; base += 8) {
                int2 np = bucket[min(base + g, end - 1)];
                bool valid = (base + g < end);
                const uint4* kp = (const uint4*)(kb + (size_t)np.x * 128 + h * 16);
                const uint4* vp = (const uint4*)(vb + (size_t)np.x * 128 + h * 16);
                uint4 k0 = kp[0], k1 = kp[1], v0 = vp[0], v1 = vp[1];
                edge_math(k0, k1, v0, v1, __int_as_float(np.y), valid);
            }
        }

#pragma unroll
        for (int off = 8; off < 64; off <<= 1) {
            l += __shfl_xor(l, off);
#pragma unroll
            for (int j = 0; j < 16; ++j) acc[j] += __shfl_xor(acc[j], off);
        }

        if (g == 0) {
            float inv = 1.0f / (l + 1e-12f);
            float4* op = (float4*)(o + (size_t)n * 128 + h * 16);
#pragma unroll
            for (int j = 0; j < 4; ++j) {
                float4 t;
                t.x = acc[j * 4 + 0] * inv; t.y = acc[j * 4 + 1] * inv;
                t.z = acc[j * 4 + 2] * inv; t.w = acc[j * 4 + 3] * inv;
                op[j] = t;
            }
        }
    }
}

// ---------------- out GEMM (128-row tile, 512 thr / 8 waves), split-bf16 MFMA K=128 ----------------
__global__ __launch_bounds__(512, 4) void out_gemm_mfma_kernel(
    const float* __restrict__ o,
    const unsigned short* __restrict__ wo_h, const unsigned short* __restrict__ wo_l,
    const float* __restrict__ bo, float* __restrict__ out, int Nn) {
    const int n0 = blockIdx.x * 128;

    __shared__ unsigned short xh_s[128 * 40];
    __shared__ unsigned short xl_s[128 * 40];
    __shared__ unsigned short wh_s[128 * 40];
    __shared__ unsigned short wl_s[128 * 40];

    const int tid = threadIdx.x;
    const int w = tid >> 6;
    const int lane = tid & 63;
    const int ml = lane & 15;
    const int quad = lane >> 4;
    const int rg = w & 3;
    const int cg = w >> 2;

    const int rows_valid = min(128, Nn - n0);

    floatx4 acc[2][4];
#pragma unroll
    for (int rr = 0; rr < 2; ++rr)
#pragma unroll
        for (int ct = 0; ct < 4; ++ct) acc[rr][ct] = (floatx4){0.f, 0.f, 0.f, 0.f};

    for (int kc = 0; kc < OUT_DIM; kc += 32) {
        {
            int r = tid >> 2, c = tid & 3;
            unsigned short hv[8], lv[8];
            if (r < rows_valid) {
                const float* src = o + (size_t)(n0 + r) * OUT_DIM + kc + c * 8;
#pragma unroll
                for (int j = 0; j < 8; ++j) split1(src[j], hv[j], lv[j]);
            } else {
#pragma unroll
                for (int j = 0; j < 8; ++j) { hv[j] = 0; lv[j] = 0; }
            }
            *(short8*)(xh_s + r * 40 + c * 8) = *(short8*)hv;
            *(short8*)(xl_s + r * 40 + c * 8) = *(short8*)lv;
            size_t gg = (size_t)r * OUT_DIM + kc + c * 8;
            *(short8*)(wh_s + r * 40 + c * 8) = *(const short8*)(wo_h + gg);
            *(short8*)(wl_s + r * 40 + c * 8) = *(const short8*)(wo_l + gg);
        }
        __syncthreads();

        short8 ah0 = *(const short8*)(xh_s + (rg * 32 + ml) * 40 + quad * 8);
        short8 ah1 = *(const short8*)(xh_s + (rg * 32 + 16 + ml) * 40 + quad * 8);
        short8 al0 = *(const short8*)(xl_s + (rg * 32 + ml) * 40 + quad * 8);
        short8 al1 = *(const short8*)(xl_s + (rg * 32 + 16 + ml) * 40 + quad * 8);
#pragma unroll
        for (int ct = 0; ct < 4; ++ct) {
            short8 bh = *(const short8*)(wh_s + (cg * 64 + ct * 16 + ml) * 40 + quad * 8);
            short8 bl = *(const short8*)(wl_s + (cg * 64 + ct * 16 + ml) * 40 + quad * 8);
            acc[0][ct] = __builtin_amdgcn_mfma_f32_16x16x32_bf16(ah0, bh, acc[0][ct], 0, 0, 0);
            acc[0][ct] = __builtin_amdgcn_mfma_f32_16x16x32_bf16(al0, bh, acc[0][ct], 0, 0, 0);
            acc[0][ct] = __builtin_amdgcn_mfma_f32_16x16x32_bf16(ah0, bl, acc[0][ct], 0, 0, 0);
            acc[1][ct] = __builtin_amdgcn_mfma_f32_16x16x32_bf16(ah1, bh, acc[1][ct], 0, 0, 0);
            acc[1][ct] = __builtin_amdgcn_mfma_f32_16x16x32_bf16(al1, bh, acc[1][ct], 0, 0, 0);
            acc[1][ct] = __builtin_amdgcn_mfma_f32_16x16x32_bf16(ah1, bl, acc[1][ct], 0, 0, 0);
        }
        __syncthreads();
    }

#pragma unroll
    for (int rr = 0; rr < 2; ++rr)
#pragma unroll
        for (int ct = 0; ct < 4; ++ct) {
            int col = cg * 64 + ct * 16 + ml;
            float bj = bo[col];
#pragma unroll
            for (int r = 0; r < 4; ++r) {
                int grow = n0 + rg * 32 + rr * 16 + quad * 4 + r;
                if (grow < Nn) out[(size_t)grow * 128 + col] = acc[rr][ct][r] + bj;
            }
        }
}

extern "C" void kernel_launch(void* const* d_in, const int* in_sizes, int n_in,
                              void* d_out, int out_size, void* d_ws, size_t ws_size,
                              hipStream_t stream) {
    const float* x   = (const float*)d_in[0];
    const int* ei    = (const int*)d_in[1];
    const float* edist = (const float*)d_in[2];
    const float* Wq = (const float*)d_in[3];  const float* bq = (const float*)d_in[4];
    const float* Wk = (const float*)d_in[5];  const float* bk = (const float*)d_in[6];
    const float* Wv = (const float*)d_in[7];  const float* bv = (const float*)d_in[8];
    const float* Wo = (const float*)d_in[9];  const float* bo = (const float*)d_in[10];
    const float* Wg1 = (const float*)d_in[11]; const float* bg1 = (const float*)d_in[12];
    const float* Wg2 = (const float*)d_in[13]; const float* bg2 = (const float*)d_in[14];
    const int Nn = in_sizes[0] / IN_DIM;
    const int Ee = in_sizes[2];
    float* out = (float*)d_out;

    char* ws = (char*)d_ws;
    size_t off = 0;
    auto alloc = [&](size_t bytes) -> char* {
        char* p = ws + off;
        off += (bytes + 255) & ~(size_t)255;
        return p;
    };
    float* q  = (float*)alloc((size_t)Nn * 128 * 4);
    unsigned short* kbuf = (unsigned short*)alloc((size_t)Nn * 128 * 2);
    unsigned short* vbuf = (unsigned short*)alloc((size_t)Nn * 128 * 2);
    char* xlblock = alloc((size_t)Nn * IN_DIM * 2);
    float* o = (float*)alloc((size_t)Nn * 128 * 4);       // f32 attention output; binbuf aliases it
    float* geot = (float*)alloc((size_t)TBL * 8 * 4);
    int2* meta = (int2*)alloc((size_t)Nn * 8);
    int nbins = (Nn + 127) >> 7;
    int* gbin = (int*)alloc((size_t)nbins * 4);
    unsigned short* wh_all = (unsigned short*)alloc((size_t)3 * OUT_DIM * IN_DIM * 2);
    unsigned short* wl_all = (unsigned short*)alloc((size_t)3 * OUT_DIM * IN_DIM * 2);
    unsigned short* wo_h = (unsigned short*)alloc((size_t)OUT_DIM * OUT_DIM * 2);
    unsigned short* wo_l = (unsigned short*)alloc((size_t)OUT_DIM * OUT_DIM * 2);
    int2* bucket = (int2*)alloc((size_t)nbins * BCAP * 8);   // 8.0 MB compact CSR-per-bin

    // binbuf aliases o: nbins*BCAP*8 = 8.0 MB <= Nn*512 B = 25.6 MB.
    // Lifetime: binbuf written in qkv dispatch (phase1), read in bin2bucket,
    // dead before fused_node writes o. No overlap.
    int2* binbuf = (int2*)o;

    unsigned short* xh = (unsigned short*)d_out;       // rewritten by final GEMM
    unsigned short* xl = (unsigned short*)xlblock;

    // --- dispatch 1: prep_all ---
    int n4x = Nn * IN_DIM / 4;
    int nsplit = (n4x + 255) / 256;
    int nwm = ((OUT_DIM * IN_DIM / 4) + 255) / 256;
    int nwo = ((OUT_DIM * OUT_DIM / 4) + 255) / 256;
    int ngeo = (TBL + 255) / 256;
    int gprep = nsplit + 3 * nwm + nwo + ngeo + 1;     // +1 block zeroes gbin
    prep_all_kernel<<<gprep, 256, 0, stream>>>(
        x, Wq, Wk, Wv, Wo, xh, xl, wh_all, wl_all, wo_h, wo_l,
        Wg1, bg1, Wg2, bg2, geot, gbin, n4x, nbins, nsplit, nwm, nwo, ngeo);

    // --- dispatch 2: [phase1 bin-scatter blocks first] + qkv GEMM blocks (512 thr) ---
    int nxb = (Nn + 127) / 128;
    int nb1 = (Ee + 4095) / 4096;
    qkv_kernel<<<nb1 + 3 * nxb, 512, 0, stream>>>(
        xh, xl, wh_all, wl_all, bq, bk, bv, q, kbuf, vbuf,
        ei, edist, gbin, binbuf, Nn, Ee, nxb, nb1, nbins);

    // --- dispatch 3: phase2 bin -> compact CSR buckets (coalesced writes) ---
    bin2bucket_kernel<<<nbins, 256, 0, stream>>>(binbuf, gbin, bucket, meta, Nn);

    // --- dispatch 4: fused edge+node (persistent grid-stride waves) ---
    {
        int nblk = 2048;
        int nwav = nblk * 4;
        fused_node_kernel<<<nblk, 256, 0, stream>>>(q, kbuf, vbuf, bucket, geot, meta, o, Nn, nwav);
    }

    // --- dispatch 5: out GEMM (128-row tiles, 512 thr) ---
    out_gemm_mfma_kernel<<<(Nn + 127) / 128, 512, 0, stream>>>(o, wo_h, wo_l, bo, out, Nn);
}

// Round 6
// 254.362 us; speedup vs baseline: 1.3184x; 1.0525x over previous
//
#include <hip/hip_runtime.h>
#include <math.h>

#define IN_DIM 256
#define OUT_DIM 128
#define NH 8
#define HD 16
#define GH 16
#define TBL 1024
#define LOG2E 1.44269504f
// R17: reallocation round.
//  - x hi/lo pre-split DELETED (was ~103 MB traffic in prep); qkv stages from
//    f32 x, splitting in-register (bit-identical). prep is now tiny (W+geo).
//  - bin2bucket: 64-row bins (782 blocks vs 391; was 1.5 blocks/CU, starved).
//  - fused_node: revert R16 persistence (regressed 63->65.7); per-node waves
//    + meta int2 + both 8-edge tiles issued up-front.
// fused_node fetch floor: ~8 XCD x 24 MB = 190 MB compulsory (matches counter);
// it is near its random-line BW floor (~3.4 TB/s) -> don't over-invest there.
#define RCAP 64
#define BINSH 6
#define BCAP 1408   // 64-row bin: Poisson(1024) + 12 sigma

typedef __attribute__((ext_vector_type(8))) short short8;
typedef __attribute__((ext_vector_type(4))) float floatx4;

// ---------------- bf16 helpers (RNE) ----------------
__device__ __forceinline__ unsigned short f2bf(float f) {
    union { float f; unsigned u; } v; v.f = f;
    unsigned r = v.u + 0x7fffu + ((v.u >> 16) & 1u);
    return (unsigned short)(r >> 16);
}
__device__ __forceinline__ float bf2f(unsigned short h) {
    union { unsigned u; float f; } v; v.u = ((unsigned)h) << 16;
    return v.f;
}
__device__ __forceinline__ void split1(float f, unsigned short& h, unsigned short& l) {
    h = f2bf(f);
    l = f2bf(f - bf2f(h));
}
__device__ __forceinline__ float bflo(unsigned u) { return __uint_as_float(u << 16); }
__device__ __forceinline__ float bfhi(unsigned u) { return __uint_as_float(u & 0xffff0000u); }

// ---------------- prep_all: split Wq/Wk/Wv/Wo, geo table, zero gbin (x-split deleted) ----------------
__global__ __launch_bounds__(256) void prep_all_kernel(
    const float* __restrict__ Wq, const float* __restrict__ Wk,
    const float* __restrict__ Wv, const float* __restrict__ Wo,
    unsigned short* __restrict__ wh, unsigned short* __restrict__ wl,
    unsigned short* __restrict__ wo_h, unsigned short* __restrict__ wo_l,
    const float* __restrict__ Wg1, const float* __restrict__ bg1,
    const float* __restrict__ Wg2, const float* __restrict__ bg2,
    float* __restrict__ tbl, int* __restrict__ gbin,
    int nbins, int nwm, int nwo, int ngeo) {
    int bx = blockIdx.x;
    int t = threadIdx.x;

    if (bx < 3 * nwm) {                      // split Wq/Wk/Wv
        int m = bx / nwm;
        int i = (bx - m * nwm) * 256 + t;
        if (i >= (OUT_DIM * IN_DIM) / 4) return;
        const float* W = (m == 0) ? Wq : (m == 1) ? Wk : Wv;
        float4 f = ((const float4*)W)[i];
        ushort4 h, l;
        split1(f.x, h.x, l.x); split1(f.y, h.y, l.y);
        split1(f.z, h.z, l.z); split1(f.w, h.w, l.w);
        size_t base = (size_t)m * (OUT_DIM * IN_DIM) / 4;
        ((ushort4*)wh)[base + i] = h;
        ((ushort4*)wl)[base + i] = l;
        return;
    }
    bx -= 3 * nwm;
    if (bx < nwo) {                          // split Wo
        int i = bx * 256 + t;
        if (i >= (OUT_DIM * OUT_DIM) / 4) return;
        float4 f = ((const float4*)Wo)[i];
        ushort4 h, l;
        split1(f.x, h.x, l.x); split1(f.y, h.y, l.y);
        split1(f.z, h.z, l.z); split1(f.w, h.w, l.w);
        ((ushort4*)wo_h)[i] = h;
        ((ushort4*)wo_l)[i] = l;
        return;
    }
    bx -= nwo;
    if (bx < ngeo) {                         // geo bias table (log2-domain)
        int i = bx * 256 + t;
        if (i >= TBL) return;
        float d = (float)i * (6.0f / (float)(TBL - 1));
        float rbf[GH];
#pragma unroll
        for (int j = 0; j < GH; ++j) {
            float c = 0.4f * (float)j;
            float tt = d - c;
            rbf[j] = __expf(-tt * tt);
        }
        float hid[GH];
#pragma unroll
        for (int j = 0; j < GH; ++j) {
            float acc = bg1[j];
#pragma unroll
            for (int kk = 0; kk < GH; ++kk) acc += rbf[kk] * Wg1[j * GH + kk];
            hid[j] = fmaxf(acc, 0.0f);
        }
#pragma unroll
        for (int h = 0; h < NH; ++h) {
            float acc = bg2[h];
#pragma unroll
            for (int j = 0; j < GH; ++j) acc += hid[j] * Wg2[h * GH + j];
            tbl[i * NH + h] = acc * LOG2E;
        }
        return;
    }
    // last block: zero gbin
    for (int i = t; i < nbins; i += 256) gbin[i] = 0;
}

// ---------------- qkv (128x128 tile, 512 thr / 8 waves, in-kernel x split) + phase-1 scatter ----------------
__global__ __launch_bounds__(512, 4) void qkv_kernel(
    const float* __restrict__ x,
    const unsigned short* __restrict__ wh, const unsigned short* __restrict__ wl,
    const float* __restrict__ bq, const float* __restrict__ bk, const float* __restrict__ bv,
    float* __restrict__ q, unsigned short* __restrict__ kb, unsigned short* __restrict__ vb,
    const int* __restrict__ ei, const float* __restrict__ edist,
    int* __restrict__ gbin, int2* __restrict__ binbuf,
    int Nn, int E_, int nxb, int nb1, int nbins) {
    __shared__ unsigned short xh_s[128 * 40];
    __shared__ unsigned short xl_s[128 * 40];
    __shared__ unsigned short wh_s[128 * 40];
    __shared__ unsigned short wl_s[128 * 40];

    const int tid = threadIdx.x;
    int bx = blockIdx.x;

    if (bx < nb1) {
        // ---- phase 1: bin scatter (runs first -> overlaps GEMM blocks) ----
        int* hist = (int*)xh_s;              // reuse LDS (nbins*4 = 3.1KB <= 10KB)
        const int e0 = bx * 4096;
        for (int b = tid; b < nbins; b += 512) hist[b] = 0;
        __syncthreads();
#pragma unroll
        for (int i = 0; i < 8; ++i) {
            int e = e0 + tid + i * 512;
            if (e < E_) atomicAdd(&hist[ei[e] >> BINSH], 1);
        }
        __syncthreads();
        for (int b = tid; b < nbins; b += 512) {
            int h = hist[b];
            int base = 0;
            if (h) base = atomicAdd(&gbin[b], h);   // ~nonzero-bins global atomics only
            hist[b] = base;
        }
        __syncthreads();
#pragma unroll
        for (int i = 0; i < 8; ++i) {
            int e = e0 + tid + i * 512;
            if (e < E_) {
                int row = ei[e];
                int bin = row >> BINSH;
                int r = atomicAdd(&hist[bin], 1);
                float u = edist[e] * ((float)(TBL - 1) / 6.0f);
                u = fminf(fmaxf(u, 0.0f), (float)(TBL - 1));
                if (r < BCAP)
                    binbuf[(size_t)bin * BCAP + r] =
                        make_int2((ei[E_ + e] & 0x1FFFF) | ((row & 63) << 17), __float_as_int(u));
            }
        }
        return;
    }
    bx -= nb1;

    const int wsel = bx / nxb;
    const int n0 = (bx - wsel * nxb) * 128;
    const unsigned short* W_h = wh + (size_t)wsel * (OUT_DIM * IN_DIM);
    const unsigned short* W_l = wl + (size_t)wsel * (OUT_DIM * IN_DIM);
    const float* bias = (wsel == 0) ? bq : (wsel == 1) ? bk : bv;
    const bool vpath = (wsel == 2);

    const int w = tid >> 6;          // 0..7
    const int lane = tid & 63;
    const int ml = lane & 15;
    const int quad = lane >> 4;
    const int rg = w & 3;            // rows rg*32 .. rg*32+31
    const int cg = w >> 2;           // cols cg*64 .. cg*64+63

    const int rows_valid = min(128, Nn - n0);

    floatx4 acc[2][4];
#pragma unroll
    for (int rr = 0; rr < 2; ++rr)
#pragma unroll
        for (int ct = 0; ct < 4; ++ct) acc[rr][ct] = (floatx4){0.f, 0.f, 0.f, 0.f};

    for (int kc = 0; kc < IN_DIM; kc += 32) {
        {
            int r = tid >> 2, c = tid & 3;   // 128 rows x 4 chunks of 8 floats
            float xf[8];
            if (r < rows_valid) {
                const float4* xs = (const float4*)(x + (size_t)(n0 + r) * IN_DIM + kc + c * 8);
                float4 a = xs[0], b = xs[1];
                xf[0] = a.x; xf[1] = a.y; xf[2] = a.z; xf[3] = a.w;
                xf[4] = b.x; xf[5] = b.y; xf[6] = b.z; xf[7] = b.w;
            } else {
#pragma unroll
                for (int j = 0; j < 8; ++j) xf[j] = 0.0f;
            }
            size_t gw = (size_t)r * IN_DIM + kc + c * 8;
            if (!vpath) {
                unsigned short hv[8];
#pragma unroll
                for (int j = 0; j < 8; ++j) hv[j] = f2bf(xf[j]);
                *(short8*)(xh_s + r * 40 + c * 8) = *(short8*)hv;
                *(short8*)(wh_s + r * 40 + c * 8) = *(const short8*)(W_h + gw);
            } else {
                unsigned short hv[8], lv[8];
#pragma unroll
                for (int j = 0; j < 8; ++j) split1(xf[j], hv[j], lv[j]);
                *(short8*)(xh_s + r * 40 + c * 8) = *(short8*)hv;
                *(short8*)(xl_s + r * 40 + c * 8) = *(short8*)lv;
                *(short8*)(wh_s + r * 40 + c * 8) = *(const short8*)(W_h + gw);
                *(short8*)(wl_s + r * 40 + c * 8) = *(const short8*)(W_l + gw);
            }
        }
        __syncthreads();

        short8 ah0 = *(const short8*)(xh_s + (rg * 32 + ml) * 40 + quad * 8);
        short8 ah1 = *(const short8*)(xh_s + (rg * 32 + 16 + ml) * 40 + quad * 8);
        if (!vpath) {
#pragma unroll
            for (int ct = 0; ct < 4; ++ct) {
                short8 bh = *(const short8*)(wh_s + (cg * 64 + ct * 16 + ml) * 40 + quad * 8);
                acc[0][ct] = __builtin_amdgcn_mfma_f32_16x16x32_bf16(ah0, bh, acc[0][ct], 0, 0, 0);
                acc[1][ct] = __builtin_amdgcn_mfma_f32_16x16x32_bf16(ah1, bh, acc[1][ct], 0, 0, 0);
            }
        } else {
            short8 al0 = *(const short8*)(xl_s + (rg * 32 + ml) * 40 + quad * 8);
            short8 al1 = *(const short8*)(xl_s + (rg * 32 + 16 + ml) * 40 + quad * 8);
#pragma unroll
            for (int ct = 0; ct < 4; ++ct) {
                short8 bh = *(const short8*)(wh_s + (cg * 64 + ct * 16 + ml) * 40 + quad * 8);
                short8 bl = *(const short8*)(wl_s + (cg * 64 + ct * 16 + ml) * 40 + quad * 8);
                acc[0][ct] = __builtin_amdgcn_mfma_f32_16x16x32_bf16(ah0, bh, acc[0][ct], 0, 0, 0);
                acc[0][ct] = __builtin_amdgcn_mfma_f32_16x16x32_bf16(al0, bh, acc[0][ct], 0, 0, 0);
                acc[0][ct] = __builtin_amdgcn_mfma_f32_16x16x32_bf16(ah0, bl, acc[0][ct], 0, 0, 0);
                acc[1][ct] = __builtin_amdgcn_mfma_f32_16x16x32_bf16(ah1, bh, acc[1][ct], 0, 0, 0);
                acc[1][ct] = __builtin_amdgcn_mfma_f32_16x16x32_bf16(al1, bh, acc[1][ct], 0, 0, 0);
                acc[1][ct] = __builtin_amdgcn_mfma_f32_16x16x32_bf16(ah1, bl, acc[1][ct], 0, 0, 0);
            }
        }
        __syncthreads();
    }

    if (wsel == 0) {
#pragma unroll
        for (int rr = 0; rr < 2; ++rr)
#pragma unroll
            for (int ct = 0; ct < 4; ++ct) {
                int col = cg * 64 + ct * 16 + ml;
                float bj = bias[col];
#pragma unroll
                for (int r = 0; r < 4; ++r) {
                    int grow = n0 + rg * 32 + rr * 16 + quad * 4 + r;
                    if (grow < Nn) q[(size_t)grow * 128 + col] = acc[rr][ct][r] + bj;
                }
            }
    } else {
        unsigned short* ob = (wsel == 1) ? kb : vb;
#pragma unroll
        for (int rr = 0; rr < 2; ++rr)
#pragma unroll
            for (int ct = 0; ct < 4; ++ct) {
                int col = cg * 64 + ct * 16 + ml;
                float bj = bias[col];
#pragma unroll
                for (int r = 0; r < 4; ++r) {
                    int grow = n0 + rg * 32 + rr * 16 + quad * 4 + r;
                    if (grow < Nn) ob[(size_t)grow * 128 + col] = f2bf(acc[rr][ct][r] + bj);
                }
            }
    }
}

// ---------------- phase 2: 64-row bins -> compact CSR (LDS rank+prefix, coalesced out) ----------------
__global__ __launch_bounds__(256) void bin2bucket_kernel(
    const int2* __restrict__ binbuf, const int* __restrict__ gbin,
    int2* __restrict__ bucket, int2* __restrict__ meta, int Nn) {
    __shared__ int rcnt[64];
    __shared__ int pref[64];
    __shared__ int2 ebuf[BCAP];
    const int bin = blockIdx.x;
    const int t = threadIdx.x;
    if (t < 64) rcnt[t] = 0;
    __syncthreads();
    int nb = gbin[bin];
    if (nb > BCAP) nb = BCAP;
    const int row0 = bin << BINSH;

    int px[6], py[6], rk[6];             // fully unrolled -> stays in VGPRs
#pragma unroll
    for (int j = 0; j < 6; ++j) {
        int i = t + j * 256;
        rk[j] = -1;
        if (i < nb) {
            int2 p = binbuf[(size_t)bin * BCAP + i];
            int rowrel = (p.x >> 17) & 63;
            int r = atomicAdd(&rcnt[rowrel], 1);
            if (r < RCAP) { px[j] = p.x & 0x1FFFF; py[j] = p.y; rk[j] = r | (rowrel << 16); }
        }
    }
    __syncthreads();
    int myclamp = 0;
    if (t < 64) { myclamp = min(rcnt[t], RCAP); pref[t] = myclamp; }
    __syncthreads();
    for (int off = 1; off < 64; off <<= 1) {
        int v = 0;
        if (t < 64 && t >= off) v = pref[t - off];
        __syncthreads();
        if (t < 64) pref[t] += v;
        __syncthreads();
    }
    // pref inclusive; exclusive start for row r = pref[r] - clamp[r]
#pragma unroll
    for (int j = 0; j < 6; ++j) {
        if (rk[j] >= 0) {
            int rowrel = rk[j] >> 16;
            int r = rk[j] & 0xFFFF;
            int pos = pref[rowrel] - min(rcnt[rowrel], RCAP) + r;
            ebuf[pos] = make_int2(px[j], py[j]);
        }
    }
    __syncthreads();
    int total = pref[63];
    const int obase = bin * BCAP;
    for (int i = t; i < total; i += 256) bucket[obase + i] = ebuf[i];   // coalesced
    if (t < 64 && row0 + t < Nn)
        meta[row0 + t] = make_int2(obase + pref[t] - myclamp, myclamp);
}

// ---------------- fused flash-style edge+node pass (per-node waves, double-tile up-front) ----------------
__global__ __launch_bounds__(256) void fused_node_kernel(
    const float* __restrict__ q, const unsigned short* __restrict__ kb,
    const unsigned short* __restrict__ vb, const int2* __restrict__ bucket,
    const float* __restrict__ tbl, const int2* __restrict__ meta,
    float* __restrict__ o, int Nn) {
    const int lane = threadIdx.x & 63;
    const int g = lane >> 3;     // edge subgroup (8 edges/tile)
    const int h = lane & 7;      // head
    const int n = blockIdx.x * 4 + (threadIdx.x >> 6);
    if (n >= Nn) return;

    const int2 m = meta[n];
    const int start = m.x;
    const int c = m.y;
    const int end = start + c;

    float qf[16];
    {
        const float4* qp = (const float4*)(q + (size_t)n * 128 + h * 16);
#pragma unroll
        for (int j = 0; j < 4; ++j) {
            float4 t = qp[j];
            qf[j * 4 + 0] = t.x; qf[j * 4 + 1] = t.y;
            qf[j * 4 + 2] = t.z; qf[j * 4 + 3] = t.w;
        }
    }

    float l = 0.0f;
    float acc[16];
#pragma unroll
    for (int j = 0; j < 16; ++j) acc[j] = 0.0f;

    auto edge_math = [&](const uint4& k0, const uint4& k1, const uint4& v0, const uint4& v1,
                         float u, bool valid) {
        unsigned kk[8] = {k0.x, k0.y, k0.z, k0.w, k1.x, k1.y, k1.z, k1.w};
        float d = 0.0f;
#pragma unroll
        for (int j = 0; j < 8; ++j) {
            d = fmaf(bflo(kk[j]), qf[2 * j], d);
            d = fmaf(bfhi(kk[j]), qf[2 * j + 1], d);
        }
        int i0 = min((int)u, TBL - 2);
        float fr = u - (float)i0;
        float t0 = tbl[i0 * NH + h];
        float t1 = tbl[i0 * NH + NH + h];
        float logit2 = fmaf(d, 0.25f * LOG2E, fmaf(fr, t1 - t0, t0));
        logit2 = fminf(logit2, 80.0f);
        if (!valid) logit2 = -1e30f;
        float p = __builtin_amdgcn_exp2f(logit2);
        l += p;
        unsigned vv[8] = {v0.x, v0.y, v0.z, v0.w, v1.x, v1.y, v1.z, v1.w};
#pragma unroll
        for (int j = 0; j < 8; ++j) {
            acc[2 * j]     = fmaf(p, bflo(vv[j]), acc[2 * j]);
            acc[2 * j + 1] = fmaf(p, bfhi(vv[j]), acc[2 * j + 1]);
        }
    };

    if (c > 0) {
        // tiles 0+1 up-front: 2 bucket + up to 8 K/V loads independent & in flight
        int2 npA = bucket[min(start + g, end - 1)];
        const bool vAv = (start + g < end);
        const bool doB = (end > start + 8);
        int2 npB = npA;
        bool vBv = false;
        if (doB) {
            npB = bucket[min(start + 8 + g, end - 1)];
            vBv = (start + 8 + g < end);
        }
        const uint4* kpA = (const uint4*)(kb + (size_t)npA.x * 128 + h * 16);
        const uint4* vpA = (const uint4*)(vb + (size_t)npA.x * 128 + h * 16);
        uint4 kA0 = kpA[0], kA1 = kpA[1], vA0 = vpA[0], vA1 = vpA[1];
        uint4 kB0, kB1, vB0, vB1;
        if (doB) {
            const uint4* kpB = (const uint4*)(kb + (size_t)npB.x * 128 + h * 16);
            const uint4* vpB = (const uint4*)(vb + (size_t)npB.x * 128 + h * 16);
            kB0 = kpB[0]; kB1 = kpB[1]; vB0 = vpB[0]; vB1 = vpB[1];
        }
        edge_math(kA0, kA1, vA0, vA1, __int_as_float(npA.y), vAv);
        if (doB) edge_math(kB0, kB1, vB0, vB1, __int_as_float(npB.y), vBv);
        // rare tail: degree > 16
        for (int base = start + 16; base < end; base += 8) {
            int2 np = bucket[min(base + g, end - 1)];
            bool valid = (base + g < end);
            const uint4* kp = (const uint4*)(kb + (size_t)np.x * 128 + h * 16);
            const uint4* vp = (const uint4*)(vb + (size_t)np.x * 128 + h * 16);
            uint4 k0 = kp[0], k1 = kp[1], v0 = vp[0], v1 = vp[1];
            edge_math(k0, k1, v0, v1, __int_as_float(np.y), valid);
        }
    }

#pragma unroll
    for (int off = 8; off < 64; off <<= 1) {
        l += __shfl_xor(l, off);
#pragma unroll
        for (int j = 0; j < 16; ++j) acc[j] += __shfl_xor(acc[j], off);
    }

    if (g == 0) {
        float inv = 1.0f / (l + 1e-12f);
        float4* op = (float4*)(o + (size_t)n * 128 + h * 16);
#pragma unroll
        for (int j = 0; j < 4; ++j) {
            float4 t;
            t.x = acc[j * 4 + 0] * inv; t.y = acc[j * 4 + 1] * inv;
            t.z = acc[j * 4 + 2] * inv; t.w = acc[j * 4 + 3] * inv;
            op[j] = t;
        }
    }
}

// ---------------- out GEMM (128-row tile, 512 thr / 8 waves), split-bf16 MFMA K=128 ----------------
__global__ __launch_bounds__(512, 4) void out_gemm_mfma_kernel(
    const float* __restrict__ o,
    const unsigned short* __restrict__ wo_h, const unsigned short* __restrict__ wo_l,
    const float* __restrict__ bo, float* __restrict__ out, int Nn) {
    const int n0 = blockIdx.x * 128;

    __shared__ unsigned short xh_s[128 * 40];
    __shared__ unsigned short xl_s[128 * 40];
    __shared__ unsigned short wh_s[128 * 40];
    __shared__ unsigned short wl_s[128 * 40];

    const int tid = threadIdx.x;
    const int w = tid >> 6;
    const int lane = tid & 63;
    const int ml = lane & 15;
    const int quad = lane >> 4;
    const int rg = w & 3;
    const int cg = w >> 2;

    const int rows_valid = min(128, Nn - n0);

    floatx4 acc[2][4];
#pragma unroll
    for (int rr = 0; rr < 2; ++rr)
#pragma unroll
        for (int ct = 0; ct < 4; ++ct) acc[rr][ct] = (floatx4){0.f, 0.f, 0.f, 0.f};

    for (int kc = 0; kc < OUT_DIM; kc += 32) {
        {
            int r = tid >> 2, c = tid & 3;
            unsigned short hv[8], lv[8];
            if (r < rows_valid) {
                const float* src = o + (size_t)(n0 + r) * OUT_DIM + kc + c * 8;
#pragma unroll
                for (int j = 0; j < 8; ++j) split1(src[j], hv[j], lv[j]);
            } else {
#pragma unroll
                for (int j = 0; j < 8; ++j) { hv[j] = 0; lv[j] = 0; }
            }
            *(short8*)(xh_s + r * 40 + c * 8) = *(short8*)hv;
            *(short8*)(xl_s + r * 40 + c * 8) = *(short8*)lv;
            size_t gg = (size_t)r * OUT_DIM + kc + c * 8;
            *(short8*)(wh_s + r * 40 + c * 8) = *(const short8*)(wo_h + gg);
            *(short8*)(wl_s + r * 40 + c * 8) = *(const short8*)(wo_l + gg);
        }
        __syncthreads();

        short8 ah0 = *(const short8*)(xh_s + (rg * 32 + ml) * 40 + quad * 8);
        short8 ah1 = *(const short8*)(xh_s + (rg * 32 + 16 + ml) * 40 + quad * 8);
        short8 al0 = *(const short8*)(xl_s + (rg * 32 + ml) * 40 + quad * 8);
        short8 al1 = *(const short8*)(xl_s + (rg * 32 + 16 + ml) * 40 + quad * 8);
#pragma unroll
        for (int ct = 0; ct < 4; ++ct) {
            short8 bh = *(const short8*)(wh_s + (cg * 64 + ct * 16 + ml) * 40 + quad * 8);
            short8 bl = *(const short8*)(wl_s + (cg * 64 + ct * 16 + ml) * 40 + quad * 8);
            acc[0][ct] = __builtin_amdgcn_mfma_f32_16x16x32_bf16(ah0, bh, acc[0][ct], 0, 0, 0);
            acc[0][ct] = __builtin_amdgcn_mfma_f32_16x16x32_bf16(al0, bh, acc[0][ct], 0, 0, 0);
            acc[0][ct] = __builtin_amdgcn_mfma_f32_16x16x32_bf16(ah0, bl, acc[0][ct], 0, 0, 0);
            acc[1][ct] = __builtin_amdgcn_mfma_f32_16x16x32_bf16(ah1, bh, acc[1][ct], 0, 0, 0);
            acc[1][ct] = __builtin_amdgcn_mfma_f32_16x16x32_bf16(al1, bh, acc[1][ct], 0, 0, 0);
            acc[1][ct] = __builtin_amdgcn_mfma_f32_16x16x32_bf16(ah1, bl, acc[1][ct], 0, 0, 0);
        }
        __syncthreads();
    }

#pragma unroll
    for (int rr = 0; rr < 2; ++rr)
#pragma unroll
        for (int ct = 0; ct < 4; ++ct) {
            int col = cg * 64 + ct * 16 + ml;
            float bj = bo[col];
#pragma unroll
            for (int r = 0; r < 4; ++r) {
                int grow = n0 + rg * 32 + rr * 16 + quad * 4 + r;
                if (grow < Nn) out[(size_t)grow * 128 + col] = acc[rr][ct][r] + bj;
            }
        }
}

extern "C" void kernel_launch(void* const* d_in, const int* in_sizes, int n_in,
                              void* d_out, int out_size, void* d_ws, size_t ws_size,
                              hipStream_t stream) {
    const float* x   = (const float*)d_in[0];
    const int* ei    = (const int*)d_in[1];
    const float* edist = (const float*)d_in[2];
    const float* Wq = (const float*)d_in[3];  const float* bq = (const float*)d_in[4];
    const float* Wk = (const float*)d_in[5];  const float* bk = (const float*)d_in[6];
    const float* Wv = (const float*)d_in[7];  const float* bv = (const float*)d_in[8];
    const float* Wo = (const float*)d_in[9];  const float* bo = (const float*)d_in[10];
    const float* Wg1 = (const float*)d_in[11]; const float* bg1 = (const float*)d_in[12];
    const float* Wg2 = (const float*)d_in[13]; const float* bg2 = (const float*)d_in[14];
    const int Nn = in_sizes[0] / IN_DIM;
    const int Ee = in_sizes[2];
    float* out = (float*)d_out;

    char* ws = (char*)d_ws;
    size_t off = 0;
    auto alloc = [&](size_t bytes) -> char* {
        char* p = ws + off;
        off += (bytes + 255) & ~(size_t)255;
        return p;
    };
    float* q  = (float*)alloc((size_t)Nn * 128 * 4);
    unsigned short* kbuf = (unsigned short*)alloc((size_t)Nn * 128 * 2);
    unsigned short* vbuf = (unsigned short*)alloc((size_t)Nn * 128 * 2);
    float* o = (float*)alloc((size_t)Nn * 128 * 4);       // f32 attention output; binbuf aliases it
    float* geot = (float*)alloc((size_t)TBL * 8 * 4);
    int2* meta = (int2*)alloc((size_t)Nn * 8);
    int nbins = (Nn + 63) >> BINSH;
    int* gbin = (int*)alloc((size_t)nbins * 4);
    unsigned short* wh_all = (unsigned short*)alloc((size_t)3 * OUT_DIM * IN_DIM * 2);
    unsigned short* wl_all = (unsigned short*)alloc((size_t)3 * OUT_DIM * IN_DIM * 2);
    unsigned short* wo_h = (unsigned short*)alloc((size_t)OUT_DIM * OUT_DIM * 2);
    unsigned short* wo_l = (unsigned short*)alloc((size_t)OUT_DIM * OUT_DIM * 2);
    int2* bucket = (int2*)alloc((size_t)nbins * BCAP * 8);   // 8.8 MB compact CSR-per-bin

    // binbuf aliases o: nbins*BCAP*8 = 8.8 MB <= Nn*512 B = 25.6 MB.
    // Lifetime: binbuf written in qkv dispatch (phase1), read in bin2bucket,
    // dead before fused_node writes o. No overlap.
    int2* binbuf = (int2*)o;

    // --- dispatch 1: prep_all (tiny: W splits + geo + gbin zero) ---
    int nwm = ((OUT_DIM * IN_DIM / 4) + 255) / 256;
    int nwo = ((OUT_DIM * OUT_DIM / 4) + 255) / 256;
    int ngeo = (TBL + 255) / 256;
    int gprep = 3 * nwm + nwo + ngeo + 1;     // +1 block zeroes gbin
    prep_all_kernel<<<gprep, 256, 0, stream>>>(
        Wq, Wk, Wv, Wo, wh_all, wl_all, wo_h, wo_l,
        Wg1, bg1, Wg2, bg2, geot, gbin, nbins, nwm, nwo, ngeo);

    // --- dispatch 2: [phase1 bin-scatter blocks first] + qkv GEMM blocks (512 thr) ---
    int nxb = (Nn + 127) / 128;
    int nb1 = (Ee + 4095) / 4096;
    qkv_kernel<<<nb1 + 3 * nxb, 512, 0, stream>>>(
        x, wh_all, wl_all, bq, bk, bv, q, kbuf, vbuf,
        ei, edist, gbin, binbuf, Nn, Ee, nxb, nb1, nbins);

    // --- dispatch 3: phase2 bin -> compact CSR buckets (coalesced writes) ---
    bin2bucket_kernel<<<nbins, 256, 0, stream>>>(binbuf, gbin, bucket, meta, Nn);

    // --- dispatch 4: fused edge+node (per-node waves, double-tile up-front) ---
    fused_node_kernel<<<(Nn + 3) / 4, 256, 0, stream>>>(q, kbuf, vbuf, bucket, geot, meta, o, Nn);

    // --- dispatch 5: out GEMM (128-row tiles, 512 thr) ---
    out_gemm_mfma_kernel<<<(Nn + 127) / 128, 512, 0, stream>>>(o, wo_h, wo_l, bo, out, Nn);
}